// Round 5
// baseline (7836.855 us; speedup 1.0000x reference)
//
#include <hip/hip_runtime.h>

#define NN 100000
#define LN_EPS 1e-5f
#define BSH 6                       // 64 nodes per bucket
#define BNODES 64
#define NBK ((NN + 63) >> 6)        // 1563 buckets
#define EC 12288                    // edges per partition chunk

typedef unsigned int uint_t;
typedef unsigned short ushort_t;
typedef __attribute__((ext_vector_type(8))) short short8v;
typedef __attribute__((ext_vector_type(4))) float f32x4;

// round-to-nearest-even f32 -> bf16
__device__ __forceinline__ ushort_t bf16_rte(float x) {
  uint_t u = __float_as_uint(x);
  u = (u + 0x7FFFu + ((u >> 16) & 1u)) >> 16;
  return (ushort_t)u;
}
__device__ __forceinline__ uint_t pack_bf16x2(float a, float b) {
  uint_t ua = __float_as_uint(a);
  ua = (ua + 0x7FFFu + ((ua >> 16) & 1u)) >> 16;
  uint_t ub = __float_as_uint(b);
  ub = (ub + 0x7FFFu + ((ub >> 16) & 1u)) & 0xFFFF0000u;
  return ua | ub;
}
__device__ __forceinline__ float bf_lo(uint_t u) { return __uint_as_float(u << 16); }
__device__ __forceinline__ float bf_hi(uint_t u) { return __uint_as_float(u & 0xFFFF0000u); }

// ---------------- degree + norm ----------------

__global__ void k_hist(const int* __restrict__ dst, int* __restrict__ deg, int E) {
  int i = blockIdx.x * 256 + threadIdx.x;
  if (i < E) atomicAdd(&deg[dst[i]], 1);
}

__global__ void k_dis(const int* __restrict__ deg, float* __restrict__ dis, int n) {
  int i = blockIdx.x * 256 + threadIdx.x;
  if (i < n) dis[i] = rsqrtf((float)(deg[i] + 1));   // +1 self loop
}

// ---------------- scan (8192 per block, 32 per thread) ----------------

__global__ __launch_bounds__(256) void k_scanA32(const int* in, int* out,
                                                 int* bsum, int n) {
  __shared__ int sh[256];
  int t = threadIdx.x;
  int base = blockIdx.x * 8192 + t * 32;
  int v[32];
  int s = 0;
#pragma unroll
  for (int i = 0; i < 32; ++i) {
    int idx = base + i;
    v[i] = (idx < n) ? in[idx] : 0;
    s += v[i];
  }
  sh[t] = s;
  __syncthreads();
  for (int d = 1; d < 256; d <<= 1) {
    int a = (t >= d) ? sh[t - d] : 0;
    __syncthreads();
    sh[t] += a;
    __syncthreads();
  }
  int run = sh[t] - s;
  if (t == 255) bsum[blockIdx.x] = sh[255];
#pragma unroll
  for (int i = 0; i < 32; ++i) {
    int idx = base + i;
    if (idx < n) out[idx] = run;
    run += v[i];
  }
}

__global__ void k_scanB(int* bsum, int nb) {
  int t = threadIdx.x;
  int x = (t < nb) ? bsum[t] : 0;
  int incl = x;
#pragma unroll
  for (int d = 1; d < 64; d <<= 1) {
    int y = __shfl_up(incl, d, 64);
    if (t >= d) incl += y;
  }
  if (t < nb) bsum[t] = incl - x;
}

__global__ void k_scanC32(int* __restrict__ rp, const int* __restrict__ bsum,
                          int n, int total) {
  int i = blockIdx.x * 256 + threadIdx.x;
  if (i < n) rp[i] += bsum[i >> 13];
  else if (i == n) rp[n] = total;
}

// ---------------- partition: per-chunk histogram over buckets ----------------
// gmatC[bucket * B + chunk] = count

__global__ __launch_bounds__(256) void k_phist(const int* __restrict__ dst,
                                               int* __restrict__ gmatC, int E, int B) {
  __shared__ int lh[NBK];
  int t = threadIdx.x;
  for (int i = t; i < NBK; i += 256) lh[i] = 0;
  __syncthreads();
  int base = blockIdx.x * EC;
  int end = min(E, base + EC);
  for (int i = base + t; i < end; i += 256) atomicAdd(&lh[dst[i] >> BSH], 1);
  __syncthreads();
  for (int b = t; b < NBK; b += 256) gmatC[(size_t)b * B + blockIdx.x] = lh[b];
}

// LDS counting sort of one chunk, coalesced segment writes to bucket-partitioned
// packed edge array: parts[pos] = (dst&63)<<20 | src
__global__ __launch_bounds__(256) void k_pscatter(const int* __restrict__ src,
                                                  const int* __restrict__ dst,
                                                  const int* __restrict__ gmatS,
                                                  uint_t* __restrict__ parts,
                                                  int E, int B) {
  __shared__ uint_t stage[EC];   // 48 KB
  __shared__ int lh[2048];       // counts -> exclusive scan (padded)
  __shared__ int lcur[NBK];
  __shared__ int sh[256];
  int t = threadIdx.x;
  int c = blockIdx.x;
  for (int i = t; i < 2048; i += 256) lh[i] = 0;
  __syncthreads();
  int base = c * EC;
  int end = min(E, base + EC);
  for (int i = base + t; i < end; i += 256) atomicAdd(&lh[dst[i] >> BSH], 1);
  __syncthreads();
  // exclusive scan of lh[0..2047] (covers NBK + total at lh[NBK])
  int loc[8];
  int s = 0;
#pragma unroll
  for (int i = 0; i < 8; ++i) {
    loc[i] = lh[t * 8 + i];
    s += loc[i];
  }
  sh[t] = s;
  __syncthreads();
  for (int d = 1; d < 256; d <<= 1) {
    int a = (t >= d) ? sh[t - d] : 0;
    __syncthreads();
    sh[t] += a;
    __syncthreads();
  }
  int run = sh[t] - s;
#pragma unroll
  for (int i = 0; i < 8; ++i) {
    int v = loc[i];
    lh[t * 8 + i] = run;
    run += v;
  }
  __syncthreads();
  for (int i = t; i < NBK; i += 256) lcur[i] = lh[i];
  __syncthreads();
  // place edges into stage in bucket order
  for (int i = base + t; i < end; i += 256) {
    int d = dst[i];
    int b = d >> BSH;
    int pos = atomicAdd(&lcur[b], 1);
    stage[pos] = ((uint_t)(d & (BNODES - 1)) << 20) | (uint_t)src[i];
  }
  __syncthreads();
  // copy per-bucket segments to global at precomputed offsets (coalesced)
  int wid = t >> 6, lane = t & 63;
  for (int b = wid; b < NBK; b += 4) {
    int s0 = lh[b];
    int s1 = lh[b + 1];
    int gb = gmatS[(size_t)b * B + c];
    for (int j = lane; j < s1 - s0; j += 64) parts[gb + j] = stage[s0 + j];
  }
}

// ---------------- fp32 -> bf16 convert ----------------

__global__ void k_cvt(const float* __restrict__ x, ushort_t* __restrict__ y, int total4) {
  int i = blockIdx.x * 256 + threadIdx.x;
  if (i < total4) {
    float4 v = *(const float4*)&x[i * 4];
    uint2 p;
    p.x = pack_bf16x2(v.x, v.y);
    p.y = pack_bf16x2(v.z, v.w);
    *(uint2*)&y[i * 4] = p;
  }
}

// ---------------- W pack: fp32 [K][128] -> bf16 MFMA B-frag order ----------------

__global__ void k_packw(const float* __restrict__ W, ushort_t* __restrict__ P) {
  int t = blockIdx.x * 256 + threadIdx.x;
  int lane = t & 63;
  int j = (t >> 6) & 7;
  int kk = t >> 9;
  int krow = kk * 32 + (lane >> 4) * 8;
  int col = j * 16 + (lane & 15);
  ushort_t o[8];
#pragma unroll
  for (int i = 0; i < 8; ++i) o[i] = bf16_rte(W[(size_t)(krow + i) * 128 + col]);
  uint4 v;
  v.x = (uint_t)o[0] | ((uint_t)o[1] << 16);
  v.y = (uint_t)o[2] | ((uint_t)o[3] << 16);
  v.z = (uint_t)o[4] | ((uint_t)o[5] << 16);
  v.w = (uint_t)o[6] | ((uint_t)o[7] << 16);
  *(uint4*)&P[(size_t)t * 8] = v;
}

// ---------------- bf16 MFMA GEMM ----------------

template <int KK, bool ENC>
__global__ __launch_bounds__(256) void k_gemm_mfma(const ushort_t* __restrict__ A,
                                                   const ushort_t* __restrict__ Wp,
                                                   const float* __restrict__ aux,
                                                   ushort_t* __restrict__ C, int n) {
  int lane = threadIdx.x & 63;
  int wid = threadIdx.x >> 6;
  int r0 = (blockIdx.x * 4 + wid) * 16;
  if (r0 >= n) return;
  int arow = r0 + (lane & 15);
  if (arow >= n) arow = n - 1;
  const ushort_t* aptr = A + (size_t)arow * (KK * 32) + (lane >> 4) * 8;

  f32x4 acc[8] = {};
#pragma unroll
  for (int kk = 0; kk < KK; ++kk) {
    short8v a = *(const short8v*)(aptr + kk * 32);
    const ushort_t* wp = Wp + ((size_t)(kk * 8) * 64 + lane) * 8;
#pragma unroll
    for (int j = 0; j < 8; ++j) {
      short8v b = *(const short8v*)(wp + (size_t)j * 512);
      acc[j] = __builtin_amdgcn_mfma_f32_16x16x32_bf16(a, b, acc[j], 0, 0, 0);
    }
  }
  int rbase = r0 + (lane >> 4) * 4;
  int colb = lane & 15;
  float bcol[8];
  if constexpr (ENC) {
#pragma unroll
    for (int j = 0; j < 8; ++j) bcol[j] = aux[j * 16 + colb];
  }
#pragma unroll
  for (int reg = 0; reg < 4; ++reg) {
    int row = rbase + reg;
    if (row < n) {
      if constexpr (ENC) {
#pragma unroll
        for (int j = 0; j < 8; ++j)
          C[(size_t)row * 128 + j * 16 + colb] = bf16_rte(fmaxf(acc[j][reg] + bcol[j], 0.f));
      } else {
        float s = aux[row];
#pragma unroll
        for (int j = 0; j < 8; ++j)
          C[(size_t)row * 128 + j * 16 + colb] = bf16_rte(acc[j][reg] * s);
      }
    }
  }
}

// ---------------- bucket aggregation + bias + LayerNorm + ReLU ----------------
// block = one 64-node bucket; fp32 accumulators in LDS; edges streamed
// sequentially; gathers by half-wave (32 lanes = full 128-ch bf16 row).

__global__ __launch_bounds__(256) void k_bagg(const uint2* __restrict__ hw2,
                                              const int* __restrict__ gmatS,
                                              const uint_t* __restrict__ parts,
                                              const float* __restrict__ dis,
                                              const float* __restrict__ bias,
                                              const float* __restrict__ gamma,
                                              const float* __restrict__ beta,
                                              uint2* __restrict__ out2, int n, int B) {
  __shared__ float accum[BNODES][128];   // 32 KB
  int t = threadIdx.x;
  int b = blockIdx.x;
  float* ap = &accum[0][0];
#pragma unroll
  for (int i = 0; i < 8; ++i)
    *(float4*)&ap[(i * 256 + t) * 4] = make_float4(0.f, 0.f, 0.f, 0.f);
  __syncthreads();

  int h = t >> 5;        // half-wave id (0..7)
  int cl = t & 31;       // lane within half-wave: channels 4cl..4cl+3
  int s0 = gmatS[(size_t)b * B];
  int s1 = gmatS[(size_t)(b + 1) * B];
  int cnt = s1 - s0;
  int nb32 = cnt >> 5;
  for (int gi = h; gi < nb32; gi += 8) {
    uint_t myu = parts[s0 + (gi << 5) + cl];
#pragma unroll 8
    for (int k = 0; k < 32; ++k) {
      uint_t u = __shfl(myu, k, 32);
      uint_t srcn = u & 0xFFFFFu;
      uint_t dl = u >> 20;
      uint2 r = hw2[(size_t)srcn * 32 + cl];
      atomicAdd(&accum[dl][cl * 4 + 0], bf_lo(r.x));
      atomicAdd(&accum[dl][cl * 4 + 1], bf_hi(r.x));
      atomicAdd(&accum[dl][cl * 4 + 2], bf_lo(r.y));
      atomicAdd(&accum[dl][cl * 4 + 3], bf_hi(r.y));
    }
  }
  // tail (< 32 edges per half-wave)
  for (int e = s0 + (nb32 << 5) + h; e < s1; e += 8) {
    uint_t u = parts[e];
    uint_t srcn = u & 0xFFFFFu;
    uint_t dl = u >> 20;
    uint2 r = hw2[(size_t)srcn * 32 + cl];
    atomicAdd(&accum[dl][cl * 4 + 0], bf_lo(r.x));
    atomicAdd(&accum[dl][cl * 4 + 1], bf_hi(r.x));
    atomicAdd(&accum[dl][cl * 4 + 2], bf_lo(r.y));
    atomicAdd(&accum[dl][cl * 4 + 3], bf_hi(r.y));
  }
  __syncthreads();

  // epilogue: one node per half-wave iteration
  int nloc = min(BNODES, n - (b << BSH));
  for (int loc = h; loc < nloc; loc += 8) {
    int node = (b << BSH) + loc;
    float4 a = *(float4*)&accum[loc][cl * 4];
    uint2 us = hw2[(size_t)node * 32 + cl];   // self loop (pre-scaled by dis)
    float a0 = a.x + bf_lo(us.x), a1 = a.y + bf_hi(us.x);
    float a2 = a.z + bf_lo(us.y), a3 = a.w + bf_hi(us.y);
    float dn = dis[node];
    float4 bb = *(const float4*)&bias[cl * 4];
    a0 = fmaf(a0, dn, bb.x);
    a1 = fmaf(a1, dn, bb.y);
    a2 = fmaf(a2, dn, bb.z);
    a3 = fmaf(a3, dn, bb.w);
    float s1v = a0 + a1 + a2 + a3;
    float s2v = a0 * a0 + a1 * a1 + a2 * a2 + a3 * a3;
#pragma unroll
    for (int m = 1; m < 32; m <<= 1) {
      s1v += __shfl_xor(s1v, m, 64);
      s2v += __shfl_xor(s2v, m, 64);
    }
    float mean = s1v * (1.0f / 128.0f);
    float var = s2v * (1.0f / 128.0f) - mean * mean;
    float rstd = rsqrtf(var + LN_EPS);
    float4 gg = *(const float4*)&gamma[cl * 4];
    float4 bl = *(const float4*)&beta[cl * 4];
    float y0 = fmaxf(fmaf((a0 - mean) * rstd, gg.x, bl.x), 0.f);
    float y1 = fmaxf(fmaf((a1 - mean) * rstd, gg.y, bl.y), 0.f);
    float y2 = fmaxf(fmaf((a2 - mean) * rstd, gg.z, bl.z), 0.f);
    float y3 = fmaxf(fmaf((a3 - mean) * rstd, gg.w, bl.w), 0.f);
    uint2 p;
    p.x = pack_bf16x2(y0, y1);
    p.y = pack_bf16x2(y2, y3);
    out2[(size_t)node * 32 + cl] = p;
  }
}

// ---------------- output head ----------------

__global__ __launch_bounds__(256) void k_out(const ushort_t* __restrict__ x1,
                                             const ushort_t* __restrict__ x2,
                                             const float* __restrict__ w,
                                             const float* __restrict__ b,
                                             float* __restrict__ out, int n) {
  __shared__ float wl[256 * 16];
  __shared__ float bl[16];
  int tid = threadIdx.x;
#pragma unroll
  for (int i = 0; i < 4; ++i) {
    int idx = (i * 256 + tid) * 4;
    *(float4*)&wl[idx] = *(const float4*)&w[idx];
  }
  if (tid < 16) bl[tid] = b[tid];
  __syncthreads();
  int node = blockIdx.x * 256 + tid;
  if (node >= n) return;
  float acc[16];
#pragma unroll
  for (int o = 0; o < 16; ++o) acc[o] = bl[o];

  const ushort_t* xr = x1 + (size_t)node * 128;
#pragma unroll 2
  for (int c = 0; c < 128; c += 8) {
    uint4 xv = *(const uint4*)&xr[c];
    float f0 = bf_lo(xv.x), f1 = bf_hi(xv.x), f2 = bf_lo(xv.y), f3 = bf_hi(xv.y);
    float f4 = bf_lo(xv.z), f5 = bf_hi(xv.z), f6 = bf_lo(xv.w), f7 = bf_hi(xv.w);
#pragma unroll
    for (int o = 0; o < 16; ++o) {
      acc[o] = fmaf(f0, wl[(c + 0) * 16 + o],
               fmaf(f1, wl[(c + 1) * 16 + o],
               fmaf(f2, wl[(c + 2) * 16 + o],
               fmaf(f3, wl[(c + 3) * 16 + o],
               fmaf(f4, wl[(c + 4) * 16 + o],
               fmaf(f5, wl[(c + 5) * 16 + o],
               fmaf(f6, wl[(c + 6) * 16 + o],
               fmaf(f7, wl[(c + 7) * 16 + o], acc[o]))))))));
    }
  }
  const ushort_t* xr2 = x2 + (size_t)node * 128;
#pragma unroll 2
  for (int c = 0; c < 128; c += 8) {
    uint4 xv = *(const uint4*)&xr2[c];
    float f0 = bf_lo(xv.x), f1 = bf_hi(xv.x), f2 = bf_lo(xv.y), f3 = bf_hi(xv.y);
    float f4 = bf_lo(xv.z), f5 = bf_hi(xv.z), f6 = bf_lo(xv.w), f7 = bf_hi(xv.w);
#pragma unroll
    for (int o = 0; o < 16; ++o) {
      acc[o] = fmaf(f0, wl[(128 + c + 0) * 16 + o],
               fmaf(f1, wl[(128 + c + 1) * 16 + o],
               fmaf(f2, wl[(128 + c + 2) * 16 + o],
               fmaf(f3, wl[(128 + c + 3) * 16 + o],
               fmaf(f4, wl[(128 + c + 4) * 16 + o],
               fmaf(f5, wl[(128 + c + 5) * 16 + o],
               fmaf(f6, wl[(128 + c + 6) * 16 + o],
               fmaf(f7, wl[(128 + c + 7) * 16 + o], acc[o]))))))));
    }
  }
#pragma unroll
  for (int o = 0; o < 4; ++o) {
    *(float4*)&out[(size_t)node * 16 + o * 4] =
        make_float4(acc[o * 4], acc[o * 4 + 1], acc[o * 4 + 2], acc[o * 4 + 3]);
  }
}

// ---------------- host ----------------

extern "C" void kernel_launch(void* const* d_in, const int* in_sizes, int n_in,
                              void* d_out, int out_size, void* d_ws, size_t ws_size,
                              hipStream_t stream) {
  const float* x = (const float*)d_in[0];
  const int* ei1 = (const int*)d_in[1];
  const int* ei2 = (const int*)d_in[2];
  const float* enc_w = (const float*)d_in[3];
  const float* enc_b = (const float*)d_in[4];
  const float* conv_w[3] = {(const float*)d_in[5], (const float*)d_in[9], (const float*)d_in[13]};
  const float* conv_b[3] = {(const float*)d_in[6], (const float*)d_in[10], (const float*)d_in[14]};
  const float* ln_g[3] = {(const float*)d_in[7], (const float*)d_in[11], (const float*)d_in[15]};
  const float* ln_b[3] = {(const float*)d_in[8], (const float*)d_in[12], (const float*)d_in[16]};
  const float* out_w = (const float*)d_in[17];
  const float* out_b = (const float*)d_in[18];
  float* out = (float*)d_out;

  const int N = NN;
  const int E = in_sizes[1] / 2;
  const int B = (E + EC - 1) / EC;       // partition chunks
  const int M = NBK * B;                 // histogram matrix size

  char* ws = (char*)d_ws;
  size_t off = 0;
  auto alloc = [&](size_t bytes) -> char* {
    char* p = ws + off;
    off += (bytes + 255) & ~(size_t)255;
    return p;
  };
  ushort_t* h0 = (ushort_t*)alloc((size_t)N * 128 * 2);
  ushort_t* hb = (ushort_t*)alloc((size_t)N * 128 * 2);
  ushort_t* p1 = (ushort_t*)alloc((size_t)N * 128 * 2);
  ushort_t* p2 = (ushort_t*)alloc((size_t)N * 128 * 2);
  ushort_t* xb = (ushort_t*)alloc((size_t)N * 64 * 2);
  ushort_t* wpk[3];
  for (int l = 0; l < 3; ++l) wpk[l] = (ushort_t*)alloc(2048 * 8 * 2);
  ushort_t* wpe = (ushort_t*)alloc(1024 * 8 * 2);

  struct G {
    int* deg; float* dis; int* gmatC; int* gmatS; int* bsum; uint_t* parts;
    const int* src; const int* dst;
  } g[2];
  for (int i = 0; i < 2; ++i) {
    g[i].deg = (int*)alloc((size_t)N * 4);
    g[i].dis = (float*)alloc((size_t)N * 4);
    g[i].gmatC = (int*)alloc((size_t)M * 4);
    g[i].gmatS = (int*)alloc((size_t)(M + 1) * 4);
    g[i].bsum = (int*)alloc(64 * 4);
    g[i].parts = (uint_t*)alloc((size_t)E * 4);
  }
  g[0].src = ei1; g[0].dst = ei1 + E;
  g[1].src = ei2; g[1].dst = ei2 + E;

  int ge = (E + 255) / 256;
  int nScan = (M + 8191) / 8192;
  for (int i = 0; i < 2; ++i) {
    hipMemsetAsync(g[i].deg, 0, (size_t)N * 4, stream);
    k_hist<<<ge, 256, 0, stream>>>(g[i].dst, g[i].deg, E);
    k_dis<<<(N + 255) / 256, 256, 0, stream>>>(g[i].deg, g[i].dis, N);
    k_phist<<<B, 256, 0, stream>>>(g[i].dst, g[i].gmatC, E, B);
    k_scanA32<<<nScan, 256, 0, stream>>>(g[i].gmatC, g[i].gmatS, g[i].bsum, M);
    k_scanB<<<1, 64, 0, stream>>>(g[i].bsum, nScan);
    k_scanC32<<<(M + 1 + 255) / 256, 256, 0, stream>>>(g[i].gmatS, g[i].bsum, M, E);
    k_pscatter<<<B, 256, 0, stream>>>(g[i].src, g[i].dst, g[i].gmatS, g[i].parts, E, B);
  }

  for (int l = 0; l < 3; ++l) k_packw<<<8, 256, 0, stream>>>(conv_w[l], wpk[l]);
  k_packw<<<4, 256, 0, stream>>>(enc_w, wpe);
  k_cvt<<<(N * 64 / 4 + 255) / 256, 256, 0, stream>>>(x, xb, N * 64 / 4);

  int gb = (N + 63) / 64;
  // shared encoder -> h0
  k_gemm_mfma<2, true><<<gb, 256, 0, stream>>>(xb, wpe, enc_b, h0, N);

  // branch 1: h0 -> ... -> x1 in p1
  {
    const ushort_t* cur = h0;
    for (int l = 0; l < 3; ++l) {
      k_gemm_mfma<4, false><<<gb, 256, 0, stream>>>(cur, wpk[l], g[0].dis, hb, N);
      k_bagg<<<NBK, 256, 0, stream>>>((const uint2*)hb, g[0].gmatS, g[0].parts,
                                      g[0].dis, conv_b[l], ln_g[l], ln_b[l],
                                      (uint2*)p1, N, B);
      cur = p1;
    }
  }
  // branch 2: h0 -> ... -> x2 in p2
  {
    const ushort_t* cur = h0;
    for (int l = 0; l < 3; ++l) {
      k_gemm_mfma<4, false><<<gb, 256, 0, stream>>>(cur, wpk[l], g[1].dis, hb, N);
      k_bagg<<<NBK, 256, 0, stream>>>((const uint2*)hb, g[1].gmatS, g[1].parts,
                                      g[1].dis, conv_b[l], ln_g[l], ln_b[l],
                                      (uint2*)p2, N, B);
      cur = p2;
    }
  }

  k_out<<<(N + 255) / 256, 256, 0, stream>>>(p1, p2, out_w, out_b, out, N);
}

// Round 6
// 1133.588 us; speedup vs baseline: 6.9133x; 6.9133x over previous
//
#include <hip/hip_runtime.h>

#define NN 100000
#define LN_EPS 1e-5f
#define BSH 6                       // 64 nodes per bucket
#define BNODES 64
#define NBK ((NN + 63) >> 6)        // 1563 buckets
#define EC 12288                    // edges per partition chunk

typedef unsigned int uint_t;
typedef unsigned short ushort_t;
typedef __attribute__((ext_vector_type(8))) short short8v;
typedef __attribute__((ext_vector_type(4))) float f32x4;

// round-to-nearest-even f32 -> bf16
__device__ __forceinline__ ushort_t bf16_rte(float x) {
  uint_t u = __float_as_uint(x);
  u = (u + 0x7FFFu + ((u >> 16) & 1u)) >> 16;
  return (ushort_t)u;
}
__device__ __forceinline__ uint_t pack_bf16x2(float a, float b) {
  uint_t ua = __float_as_uint(a);
  ua = (ua + 0x7FFFu + ((ua >> 16) & 1u)) >> 16;
  uint_t ub = __float_as_uint(b);
  ub = (ub + 0x7FFFu + ((ub >> 16) & 1u)) & 0xFFFF0000u;
  return ua | ub;
}
__device__ __forceinline__ float bf_lo(uint_t u) { return __uint_as_float(u << 16); }
__device__ __forceinline__ float bf_hi(uint_t u) { return __uint_as_float(u & 0xFFFF0000u); }

// ---------------- degree + norm ----------------

__global__ void k_hist(const int* __restrict__ dst, int* __restrict__ deg, int E) {
  int i = blockIdx.x * 256 + threadIdx.x;
  if (i < E) atomicAdd(&deg[dst[i]], 1);
}

__global__ void k_dis(const int* __restrict__ deg, float* __restrict__ dis, int n) {
  int i = blockIdx.x * 256 + threadIdx.x;
  if (i < n) dis[i] = rsqrtf((float)(deg[i] + 1));   // +1 self loop
}

// ---------------- scan (8192 per block, 32 per thread) ----------------

__global__ __launch_bounds__(256) void k_scanA32(const int* in, int* out,
                                                 int* bsum, int n) {
  __shared__ int sh[256];
  int t = threadIdx.x;
  int base = blockIdx.x * 8192 + t * 32;
  int v[32];
  int s = 0;
#pragma unroll
  for (int i = 0; i < 32; ++i) {
    int idx = base + i;
    v[i] = (idx < n) ? in[idx] : 0;
    s += v[i];
  }
  sh[t] = s;
  __syncthreads();
  for (int d = 1; d < 256; d <<= 1) {
    int a = (t >= d) ? sh[t - d] : 0;
    __syncthreads();
    sh[t] += a;
    __syncthreads();
  }
  int run = sh[t] - s;
  if (t == 255) bsum[blockIdx.x] = sh[255];
#pragma unroll
  for (int i = 0; i < 32; ++i) {
    int idx = base + i;
    if (idx < n) out[idx] = run;
    run += v[i];
  }
}

__global__ void k_scanB(int* bsum, int nb) {
  int t = threadIdx.x;
  int x = (t < nb) ? bsum[t] : 0;
  int incl = x;
#pragma unroll
  for (int d = 1; d < 64; d <<= 1) {
    int y = __shfl_up(incl, d, 64);
    if (t >= d) incl += y;
  }
  if (t < nb) bsum[t] = incl - x;
}

__global__ void k_scanC32(int* __restrict__ rp, const int* __restrict__ bsum,
                          int n, int total) {
  int i = blockIdx.x * 256 + threadIdx.x;
  if (i < n) rp[i] += bsum[i >> 13];
  else if (i == n) rp[n] = total;
}

// ---------------- partition: per-chunk histogram over buckets ----------------

__global__ __launch_bounds__(256) void k_phist(const int* __restrict__ dst,
                                               int* __restrict__ gmatC, int E, int B) {
  __shared__ int lh[NBK];
  int t = threadIdx.x;
  for (int i = t; i < NBK; i += 256) lh[i] = 0;
  __syncthreads();
  int base = blockIdx.x * EC;
  int end = min(E, base + EC);
  for (int i = base + t; i < end; i += 256) atomicAdd(&lh[dst[i] >> BSH], 1);
  __syncthreads();
  for (int b = t; b < NBK; b += 256) gmatC[(size_t)b * B + blockIdx.x] = lh[b];
}

// LDS counting sort of one chunk, coalesced segment writes to bucket-partitioned
// packed edge array: parts[pos] = (dst&63)<<20 | src
__global__ __launch_bounds__(256) void k_pscatter(const int* __restrict__ src,
                                                  const int* __restrict__ dst,
                                                  const int* __restrict__ gmatS,
                                                  uint_t* __restrict__ parts,
                                                  int E, int B) {
  __shared__ uint_t stage[EC];   // 48 KB
  __shared__ int lh[2048];
  __shared__ int lcur[NBK];
  __shared__ int sh[256];
  int t = threadIdx.x;
  int c = blockIdx.x;
  for (int i = t; i < 2048; i += 256) lh[i] = 0;
  __syncthreads();
  int base = c * EC;
  int end = min(E, base + EC);
  for (int i = base + t; i < end; i += 256) atomicAdd(&lh[dst[i] >> BSH], 1);
  __syncthreads();
  int loc[8];
  int s = 0;
#pragma unroll
  for (int i = 0; i < 8; ++i) {
    loc[i] = lh[t * 8 + i];
    s += loc[i];
  }
  sh[t] = s;
  __syncthreads();
  for (int d = 1; d < 256; d <<= 1) {
    int a = (t >= d) ? sh[t - d] : 0;
    __syncthreads();
    sh[t] += a;
    __syncthreads();
  }
  int run = sh[t] - s;
#pragma unroll
  for (int i = 0; i < 8; ++i) {
    int v = loc[i];
    lh[t * 8 + i] = run;
    run += v;
  }
  __syncthreads();
  for (int i = t; i < NBK; i += 256) lcur[i] = lh[i];
  __syncthreads();
  for (int i = base + t; i < end; i += 256) {
    int d = dst[i];
    int b = d >> BSH;
    int pos = atomicAdd(&lcur[b], 1);
    stage[pos] = ((uint_t)(d & (BNODES - 1)) << 20) | (uint_t)src[i];
  }
  __syncthreads();
  int wid = t >> 6, lane = t & 63;
  for (int b = wid; b < NBK; b += 4) {
    int s0 = lh[b];
    int s1 = lh[b + 1];
    int gb = gmatS[(size_t)b * B + c];
    for (int j = lane; j < s1 - s0; j += 64) parts[gb + j] = stage[s0 + j];
  }
}

// ---------------- bucket segment -> CSR (no sort needed) ----------------
// all edges of bucket b are exactly nodes [b*64, b*64+64); rp gives exact
// per-node offsets. Writes land in a contiguous ~4KB window (L2-local).

__global__ __launch_bounds__(256) void k_sort2(const uint_t* __restrict__ parts,
                                               const int* __restrict__ gmatS,
                                               const int* __restrict__ rp,
                                               int* __restrict__ csrc, int B, int n) {
  __shared__ int lcur[BNODES];
  int t = threadIdx.x;
  int b = blockIdx.x;
  if (t < BNODES) {
    int idx = (b << BSH) + t;
    lcur[t] = rp[min(idx, n)];
  }
  __syncthreads();
  int s0 = gmatS[(size_t)b * B];
  int s1 = gmatS[(size_t)(b + 1) * B];
  for (int i = s0 + t; i < s1; i += 256) {
    uint_t u = parts[i];
    int dl = u >> 20;
    int pos = atomicAdd(&lcur[dl], 1);
    csrc[pos] = (int)(u & 0xFFFFFu);
  }
}

// ---------------- fp32 -> bf16 convert ----------------

__global__ void k_cvt(const float* __restrict__ x, ushort_t* __restrict__ y, int total4) {
  int i = blockIdx.x * 256 + threadIdx.x;
  if (i < total4) {
    float4 v = *(const float4*)&x[i * 4];
    uint2 p;
    p.x = pack_bf16x2(v.x, v.y);
    p.y = pack_bf16x2(v.z, v.w);
    *(uint2*)&y[i * 4] = p;
  }
}

// ---------------- W pack: fp32 [K][128] -> bf16 MFMA B-frag order ----------------

__global__ void k_packw(const float* __restrict__ W, ushort_t* __restrict__ P) {
  int t = blockIdx.x * 256 + threadIdx.x;
  int lane = t & 63;
  int j = (t >> 6) & 7;
  int kk = t >> 9;
  int krow = kk * 32 + (lane >> 4) * 8;
  int col = j * 16 + (lane & 15);
  ushort_t o[8];
#pragma unroll
  for (int i = 0; i < 8; ++i) o[i] = bf16_rte(W[(size_t)(krow + i) * 128 + col]);
  uint4 v;
  v.x = (uint_t)o[0] | ((uint_t)o[1] << 16);
  v.y = (uint_t)o[2] | ((uint_t)o[3] << 16);
  v.z = (uint_t)o[4] | ((uint_t)o[5] << 16);
  v.w = (uint_t)o[6] | ((uint_t)o[7] << 16);
  *(uint4*)&P[(size_t)t * 8] = v;
}

// ---------------- bf16 MFMA GEMM ----------------

template <int KK, bool ENC>
__global__ __launch_bounds__(256) void k_gemm_mfma(const ushort_t* __restrict__ A,
                                                   const ushort_t* __restrict__ Wp,
                                                   const float* __restrict__ aux,
                                                   ushort_t* __restrict__ C, int n) {
  int lane = threadIdx.x & 63;
  int wid = threadIdx.x >> 6;
  int r0 = (blockIdx.x * 4 + wid) * 16;
  if (r0 >= n) return;
  int arow = r0 + (lane & 15);
  if (arow >= n) arow = n - 1;
  const ushort_t* aptr = A + (size_t)arow * (KK * 32) + (lane >> 4) * 8;

  f32x4 acc[8] = {};
#pragma unroll
  for (int kk = 0; kk < KK; ++kk) {
    short8v a = *(const short8v*)(aptr + kk * 32);
    const ushort_t* wp = Wp + ((size_t)(kk * 8) * 64 + lane) * 8;
#pragma unroll
    for (int j = 0; j < 8; ++j) {
      short8v b = *(const short8v*)(wp + (size_t)j * 512);
      acc[j] = __builtin_amdgcn_mfma_f32_16x16x32_bf16(a, b, acc[j], 0, 0, 0);
    }
  }
  int rbase = r0 + (lane >> 4) * 4;
  int colb = lane & 15;
  float bcol[8];
  if constexpr (ENC) {
#pragma unroll
    for (int j = 0; j < 8; ++j) bcol[j] = aux[j * 16 + colb];
  }
#pragma unroll
  for (int reg = 0; reg < 4; ++reg) {
    int row = rbase + reg;
    if (row < n) {
      if constexpr (ENC) {
#pragma unroll
        for (int j = 0; j < 8; ++j)
          C[(size_t)row * 128 + j * 16 + colb] = bf16_rte(fmaxf(acc[j][reg] + bcol[j], 0.f));
      } else {
        float s = aux[row];
#pragma unroll
        for (int j = 0; j < 8; ++j)
          C[(size_t)row * 128 + j * 16 + colb] = bf16_rte(acc[j][reg] * s);
      }
    }
  }
}

// ---------------- aggregation + bias + LayerNorm + ReLU (bf16 in/out) ----------------
// one wave per node; quarter-waves (16 lanes = full 128-ch row via uint4) process
// interleaved edges; unroll-2 -> 8 outstanding gathers per wave.

__global__ __launch_bounds__(256) void k_agg(const uint4* __restrict__ hw4,  // [n][16]
                                             const int* __restrict__ rp,
                                             const int* __restrict__ csrc,
                                             const float* __restrict__ dis,
                                             const float* __restrict__ bias,
                                             const float* __restrict__ g,
                                             const float* __restrict__ bln,
                                             uint4* __restrict__ out4, int n) {
  int lane = threadIdx.x & 63;
  int q = lane >> 4;     // quarter 0..3
  int cl = lane & 15;    // channels 8cl..8cl+7
  int node = blockIdx.x * 4 + (threadIdx.x >> 6);
  if (node >= n) return;
  int start = rp[node], end = rp[node + 1];
  float a0 = 0.f, a1 = 0.f, a2 = 0.f, a3 = 0.f, a4 = 0.f, a5 = 0.f, a6 = 0.f, a7 = 0.f;
  int e = start + q;
  for (; e + 4 < end; e += 8) {
    int s0 = csrc[e], s1 = csrc[e + 4];
    uint4 u = hw4[(size_t)s0 * 16 + cl];
    uint4 v = hw4[(size_t)s1 * 16 + cl];
    a0 += bf_lo(u.x); a1 += bf_hi(u.x); a2 += bf_lo(u.y); a3 += bf_hi(u.y);
    a4 += bf_lo(u.z); a5 += bf_hi(u.z); a6 += bf_lo(u.w); a7 += bf_hi(u.w);
    a0 += bf_lo(v.x); a1 += bf_hi(v.x); a2 += bf_lo(v.y); a3 += bf_hi(v.y);
    a4 += bf_lo(v.z); a5 += bf_hi(v.z); a6 += bf_lo(v.w); a7 += bf_hi(v.w);
  }
  if (e < end) {
    int s0 = csrc[e];
    uint4 u = hw4[(size_t)s0 * 16 + cl];
    a0 += bf_lo(u.x); a1 += bf_hi(u.x); a2 += bf_lo(u.y); a3 += bf_hi(u.y);
    a4 += bf_lo(u.z); a5 += bf_hi(u.z); a6 += bf_lo(u.w); a7 += bf_hi(u.w);
  }
  // combine the 4 quarters (each holds the same 8 channels for disjoint edges)
#pragma unroll
  for (int m = 16; m < 64; m <<= 1) {
    a0 += __shfl_xor(a0, m, 64); a1 += __shfl_xor(a1, m, 64);
    a2 += __shfl_xor(a2, m, 64); a3 += __shfl_xor(a3, m, 64);
    a4 += __shfl_xor(a4, m, 64); a5 += __shfl_xor(a5, m, 64);
    a6 += __shfl_xor(a6, m, 64); a7 += __shfl_xor(a7, m, 64);
  }
  // self loop (rows pre-scaled by dis[src]); then * dis[node] + bias
  uint4 us = hw4[(size_t)node * 16 + cl];
  a0 += bf_lo(us.x); a1 += bf_hi(us.x); a2 += bf_lo(us.y); a3 += bf_hi(us.y);
  a4 += bf_lo(us.z); a5 += bf_hi(us.z); a6 += bf_lo(us.w); a7 += bf_hi(us.w);
  float dn = dis[node];
  float4 b0 = *(const float4*)&bias[cl * 8];
  float4 b1 = *(const float4*)&bias[cl * 8 + 4];
  a0 = fmaf(a0, dn, b0.x); a1 = fmaf(a1, dn, b0.y);
  a2 = fmaf(a2, dn, b0.z); a3 = fmaf(a3, dn, b0.w);
  a4 = fmaf(a4, dn, b1.x); a5 = fmaf(a5, dn, b1.y);
  a6 = fmaf(a6, dn, b1.z); a7 = fmaf(a7, dn, b1.w);
  // LayerNorm over 128 channels: reduce within each 16-lane quarter
  float s1v = a0 + a1 + a2 + a3 + a4 + a5 + a6 + a7;
  float s2v = a0 * a0 + a1 * a1 + a2 * a2 + a3 * a3 +
              a4 * a4 + a5 * a5 + a6 * a6 + a7 * a7;
#pragma unroll
  for (int m = 1; m < 16; m <<= 1) {
    s1v += __shfl_xor(s1v, m, 64);
    s2v += __shfl_xor(s2v, m, 64);
  }
  float mean = s1v * (1.0f / 128.0f);
  float var = s2v * (1.0f / 128.0f) - mean * mean;
  float rstd = rsqrtf(var + LN_EPS);
  float4 g0 = *(const float4*)&g[cl * 8];
  float4 g1 = *(const float4*)&g[cl * 8 + 4];
  float4 l0 = *(const float4*)&bln[cl * 8];
  float4 l1 = *(const float4*)&bln[cl * 8 + 4];
  float y0 = fmaxf(fmaf((a0 - mean) * rstd, g0.x, l0.x), 0.f);
  float y1 = fmaxf(fmaf((a1 - mean) * rstd, g0.y, l0.y), 0.f);
  float y2 = fmaxf(fmaf((a2 - mean) * rstd, g0.z, l0.z), 0.f);
  float y3 = fmaxf(fmaf((a3 - mean) * rstd, g0.w, l0.w), 0.f);
  float y4 = fmaxf(fmaf((a4 - mean) * rstd, g1.x, l1.x), 0.f);
  float y5 = fmaxf(fmaf((a5 - mean) * rstd, g1.y, l1.y), 0.f);
  float y6 = fmaxf(fmaf((a6 - mean) * rstd, g1.z, l1.z), 0.f);
  float y7 = fmaxf(fmaf((a7 - mean) * rstd, g1.w, l1.w), 0.f);
  if (q == 0) {
    uint4 p;
    p.x = pack_bf16x2(y0, y1);
    p.y = pack_bf16x2(y2, y3);
    p.z = pack_bf16x2(y4, y5);
    p.w = pack_bf16x2(y6, y7);
    out4[(size_t)node * 16 + cl] = p;
  }
}

// ---------------- output head ----------------

__global__ __launch_bounds__(256) void k_out(const ushort_t* __restrict__ x1,
                                             const ushort_t* __restrict__ x2,
                                             const float* __restrict__ w,
                                             const float* __restrict__ b,
                                             float* __restrict__ out, int n) {
  __shared__ float wl[256 * 16];
  __shared__ float bl[16];
  int tid = threadIdx.x;
#pragma unroll
  for (int i = 0; i < 4; ++i) {
    int idx = (i * 256 + tid) * 4;
    *(float4*)&wl[idx] = *(const float4*)&w[idx];
  }
  if (tid < 16) bl[tid] = b[tid];
  __syncthreads();
  int node = blockIdx.x * 256 + tid;
  if (node >= n) return;
  float acc[16];
#pragma unroll
  for (int o = 0; o < 16; ++o) acc[o] = bl[o];

  const ushort_t* xr = x1 + (size_t)node * 128;
#pragma unroll 2
  for (int c = 0; c < 128; c += 8) {
    uint4 xv = *(const uint4*)&xr[c];
    float f0 = bf_lo(xv.x), f1 = bf_hi(xv.x), f2 = bf_lo(xv.y), f3 = bf_hi(xv.y);
    float f4 = bf_lo(xv.z), f5 = bf_hi(xv.z), f6 = bf_lo(xv.w), f7 = bf_hi(xv.w);
#pragma unroll
    for (int o = 0; o < 16; ++o) {
      acc[o] = fmaf(f0, wl[(c + 0) * 16 + o],
               fmaf(f1, wl[(c + 1) * 16 + o],
               fmaf(f2, wl[(c + 2) * 16 + o],
               fmaf(f3, wl[(c + 3) * 16 + o],
               fmaf(f4, wl[(c + 4) * 16 + o],
               fmaf(f5, wl[(c + 5) * 16 + o],
               fmaf(f6, wl[(c + 6) * 16 + o],
               fmaf(f7, wl[(c + 7) * 16 + o], acc[o]))))))));
    }
  }
  const ushort_t* xr2 = x2 + (size_t)node * 128;
#pragma unroll 2
  for (int c = 0; c < 128; c += 8) {
    uint4 xv = *(const uint4*)&xr2[c];
    float f0 = bf_lo(xv.x), f1 = bf_hi(xv.x), f2 = bf_lo(xv.y), f3 = bf_hi(xv.y);
    float f4 = bf_lo(xv.z), f5 = bf_hi(xv.z), f6 = bf_lo(xv.w), f7 = bf_hi(xv.w);
#pragma unroll
    for (int o = 0; o < 16; ++o) {
      acc[o] = fmaf(f0, wl[(128 + c + 0) * 16 + o],
               fmaf(f1, wl[(128 + c + 1) * 16 + o],
               fmaf(f2, wl[(128 + c + 2) * 16 + o],
               fmaf(f3, wl[(128 + c + 3) * 16 + o],
               fmaf(f4, wl[(128 + c + 4) * 16 + o],
               fmaf(f5, wl[(128 + c + 5) * 16 + o],
               fmaf(f6, wl[(128 + c + 6) * 16 + o],
               fmaf(f7, wl[(128 + c + 7) * 16 + o], acc[o]))))))));
    }
  }
#pragma unroll
  for (int o = 0; o < 4; ++o) {
    *(float4*)&out[(size_t)node * 16 + o * 4] =
        make_float4(acc[o * 4], acc[o * 4 + 1], acc[o * 4 + 2], acc[o * 4 + 3]);
  }
}

// ---------------- host ----------------

extern "C" void kernel_launch(void* const* d_in, const int* in_sizes, int n_in,
                              void* d_out, int out_size, void* d_ws, size_t ws_size,
                              hipStream_t stream) {
  const float* x = (const float*)d_in[0];
  const int* ei1 = (const int*)d_in[1];
  const int* ei2 = (const int*)d_in[2];
  const float* enc_w = (const float*)d_in[3];
  const float* enc_b = (const float*)d_in[4];
  const float* conv_w[3] = {(const float*)d_in[5], (const float*)d_in[9], (const float*)d_in[13]};
  const float* conv_b[3] = {(const float*)d_in[6], (const float*)d_in[10], (const float*)d_in[14]};
  const float* ln_g[3] = {(const float*)d_in[7], (const float*)d_in[11], (const float*)d_in[15]};
  const float* ln_b[3] = {(const float*)d_in[8], (const float*)d_in[12], (const float*)d_in[16]};
  const float* out_w = (const float*)d_in[17];
  const float* out_b = (const float*)d_in[18];
  float* out = (float*)d_out;

  const int N = NN;
  const int E = in_sizes[1] / 2;
  const int B = (E + EC - 1) / EC;       // partition chunks
  const int M = NBK * B;                 // histogram matrix size

  char* ws = (char*)d_ws;
  size_t off = 0;
  auto alloc = [&](size_t bytes) -> char* {
    char* p = ws + off;
    off += (bytes + 255) & ~(size_t)255;
    return p;
  };
  ushort_t* h0 = (ushort_t*)alloc((size_t)N * 128 * 2);
  ushort_t* hb = (ushort_t*)alloc((size_t)N * 128 * 2);
  ushort_t* p1 = (ushort_t*)alloc((size_t)N * 128 * 2);
  ushort_t* p2 = (ushort_t*)alloc((size_t)N * 128 * 2);
  ushort_t* xb = (ushort_t*)alloc((size_t)N * 64 * 2);
  ushort_t* wpk[3];
  for (int l = 0; l < 3; ++l) wpk[l] = (ushort_t*)alloc(2048 * 8 * 2);
  ushort_t* wpe = (ushort_t*)alloc(1024 * 8 * 2);

  struct G {
    int* deg; float* dis; int* rp; int* gmatC; int* gmatS; int* bsum;
    uint_t* parts; int* csrc; const int* src; const int* dst;
  } g[2];
  for (int i = 0; i < 2; ++i) {
    g[i].deg = (int*)alloc((size_t)N * 4);
    g[i].dis = (float*)alloc((size_t)N * 4);
    g[i].rp = (int*)alloc((size_t)(N + 1) * 4);
    g[i].gmatC = (int*)alloc((size_t)M * 4);
    g[i].gmatS = (int*)alloc((size_t)(M + 1) * 4);
    g[i].bsum = (int*)alloc(64 * 4);
    g[i].parts = (uint_t*)alloc((size_t)E * 4);
    g[i].csrc = (int*)alloc((size_t)E * 4);
  }
  g[0].src = ei1; g[0].dst = ei1 + E;
  g[1].src = ei2; g[1].dst = ei2 + E;

  int ge = (E + 255) / 256;
  int nScanN = (N + 8191) / 8192;
  int nScanM = (M + 8191) / 8192;
  for (int i = 0; i < 2; ++i) {
    hipMemsetAsync(g[i].deg, 0, (size_t)N * 4, stream);
    k_hist<<<ge, 256, 0, stream>>>(g[i].dst, g[i].deg, E);
    k_dis<<<(N + 255) / 256, 256, 0, stream>>>(g[i].deg, g[i].dis, N);
    // rp = exclusive scan of deg over N (+ rp[N]=E)
    k_scanA32<<<nScanN, 256, 0, stream>>>(g[i].deg, g[i].rp, g[i].bsum, N);
    k_scanB<<<1, 64, 0, stream>>>(g[i].bsum, nScanN);
    k_scanC32<<<(N + 1 + 255) / 256, 256, 0, stream>>>(g[i].rp, g[i].bsum, N, E);
    // bucket partition
    k_phist<<<B, 256, 0, stream>>>(g[i].dst, g[i].gmatC, E, B);
    k_scanA32<<<nScanM, 256, 0, stream>>>(g[i].gmatC, g[i].gmatS, g[i].bsum, M);
    k_scanB<<<1, 64, 0, stream>>>(g[i].bsum, nScanM);
    k_scanC32<<<(M + 1 + 255) / 256, 256, 0, stream>>>(g[i].gmatS, g[i].bsum, M, E);
    k_pscatter<<<B, 256, 0, stream>>>(g[i].src, g[i].dst, g[i].gmatS, g[i].parts, E, B);
    // bucket segments -> CSR (localized writes, no sort)
    k_sort2<<<NBK, 256, 0, stream>>>(g[i].parts, g[i].gmatS, g[i].rp, g[i].csrc, B, N);
  }

  for (int l = 0; l < 3; ++l) k_packw<<<8, 256, 0, stream>>>(conv_w[l], wpk[l]);
  k_packw<<<4, 256, 0, stream>>>(enc_w, wpe);
  k_cvt<<<(N * 64 / 4 + 255) / 256, 256, 0, stream>>>(x, xb, N * 64 / 4);

  int gb = (N + 63) / 64;
  // shared encoder -> h0
  k_gemm_mfma<2, true><<<gb, 256, 0, stream>>>(xb, wpe, enc_b, h0, N);

  // branch 1: h0 -> ... -> x1 in p1
  {
    const ushort_t* cur = h0;
    for (int l = 0; l < 3; ++l) {
      k_gemm_mfma<4, false><<<gb, 256, 0, stream>>>(cur, wpk[l], g[0].dis, hb, N);
      k_agg<<<(N + 3) / 4, 256, 0, stream>>>((const uint4*)hb, g[0].rp, g[0].csrc,
                                             g[0].dis, conv_b[l], ln_g[l], ln_b[l],
                                             (uint4*)p1, N);
      cur = p1;
    }
  }
  // branch 2: h0 -> ... -> x2 in p2
  {
    const ushort_t* cur = h0;
    for (int l = 0; l < 3; ++l) {
      k_gemm_mfma<4, false><<<gb, 256, 0, stream>>>(cur, wpk[l], g[1].dis, hb, N);
      k_agg<<<(N + 3) / 4, 256, 0, stream>>>((const uint4*)hb, g[1].rp, g[1].csrc,
                                             g[1].dis, conv_b[l], ln_g[l], ln_b[l],
                                             (uint4*)p2, N);
      cur = p2;
    }
  }

  k_out<<<(N + 255) / 256, 256, 0, stream>>>(p1, p2, out_w, out_b, out, N);
}

// Round 7
// 893.007 us; speedup vs baseline: 8.7758x; 1.2694x over previous
//
#include <hip/hip_runtime.h>

#define NN 100000
#define LN_EPS 1e-5f
#define BSH 6                       // 64 nodes per bucket
#define BNODES 64
#define NBK ((NN + 63) >> 6)        // 1563 buckets
#define EC 6144                     // edges per partition chunk

typedef unsigned int uint_t;
typedef unsigned short ushort_t;
typedef __attribute__((ext_vector_type(8))) short short8v;
typedef __attribute__((ext_vector_type(4))) float f32x4;

// round-to-nearest-even f32 -> bf16
__device__ __forceinline__ ushort_t bf16_rte(float x) {
  uint_t u = __float_as_uint(x);
  u = (u + 0x7FFFu + ((u >> 16) & 1u)) >> 16;
  return (ushort_t)u;
}
__device__ __forceinline__ uint_t pack_bf16x2(float a, float b) {
  uint_t ua = __float_as_uint(a);
  ua = (ua + 0x7FFFu + ((ua >> 16) & 1u)) >> 16;
  uint_t ub = __float_as_uint(b);
  ub = (ub + 0x7FFFu + ((ub >> 16) & 1u)) & 0xFFFF0000u;
  return ua | ub;
}
__device__ __forceinline__ float bf_lo(uint_t u) { return __uint_as_float(u << 16); }
__device__ __forceinline__ float bf_hi(uint_t u) { return __uint_as_float(u & 0xFFFF0000u); }

// ---------------- degree + norm ----------------

__global__ void k_hist(const int* __restrict__ dst, int* __restrict__ deg, int E) {
  int i = blockIdx.x * 256 + threadIdx.x;
  if (i < E) atomicAdd(&deg[dst[i]], 1);
}

__global__ void k_dis(const int* __restrict__ deg, float* __restrict__ dis, int n) {
  int i = blockIdx.x * 256 + threadIdx.x;
  if (i < n) dis[i] = rsqrtf((float)(deg[i] + 1));   // +1 self loop
}

// ---------------- scan (8192 per block, 32 per thread) ----------------

__global__ __launch_bounds__(256) void k_scanA32(const int* in, int* out,
                                                 int* bsum, int n) {
  __shared__ int sh[256];
  int t = threadIdx.x;
  int base = blockIdx.x * 8192 + t * 32;
  int v[32];
  int s = 0;
#pragma unroll
  for (int i = 0; i < 32; ++i) {
    int idx = base + i;
    v[i] = (idx < n) ? in[idx] : 0;
    s += v[i];
  }
  sh[t] = s;
  __syncthreads();
  for (int d = 1; d < 256; d <<= 1) {
    int a = (t >= d) ? sh[t - d] : 0;
    __syncthreads();
    sh[t] += a;
    __syncthreads();
  }
  int run = sh[t] - s;
  if (t == 255) bsum[blockIdx.x] = sh[255];
#pragma unroll
  for (int i = 0; i < 32; ++i) {
    int idx = base + i;
    if (idx < n) out[idx] = run;
    run += v[i];
  }
}

__global__ void k_scanB(int* bsum, int nb) {
  int t = threadIdx.x;
  int x = (t < nb) ? bsum[t] : 0;
  int incl = x;
#pragma unroll
  for (int d = 1; d < 64; d <<= 1) {
    int y = __shfl_up(incl, d, 64);
    if (t >= d) incl += y;
  }
  if (t < nb) bsum[t] = incl - x;
}

__global__ void k_scanC32(int* __restrict__ rp, const int* __restrict__ bsum,
                          int n, int total) {
  int i = blockIdx.x * 256 + threadIdx.x;
  if (i < n) rp[i] += bsum[i >> 13];
  else if (i == n) rp[n] = total;
}

// ---------------- partition: per-chunk histogram over buckets ----------------

__global__ __launch_bounds__(256) void k_phist(const int* __restrict__ dst,
                                               int* __restrict__ gmatC, int E, int B) {
  __shared__ int lh[NBK];
  int t = threadIdx.x;
  for (int i = t; i < NBK; i += 256) lh[i] = 0;
  __syncthreads();
  int base = blockIdx.x * EC;
  int end = min(E, base + EC);
  for (int i = base + t; i < end; i += 256) atomicAdd(&lh[dst[i] >> BSH], 1);
  __syncthreads();
  for (int b = t; b < NBK; b += 256) gmatC[(size_t)b * B + blockIdx.x] = lh[b];
}

// LDS counting sort of one chunk; copy-out is a FLAT loop over stage positions
// with binary search on the scan array -> all 256 lanes active, coalesced writes.
// parts[pos] = (dst&63)<<20 | src
__global__ __launch_bounds__(256) void k_pscatter(const int* __restrict__ src,
                                                  const int* __restrict__ dst,
                                                  const int* __restrict__ gmatS,
                                                  uint_t* __restrict__ parts,
                                                  int E, int B) {
  __shared__ uint_t stage[EC];   // 24 KB
  __shared__ int lh[2048];       // counts -> exclusive scan (NBK+1 <= 2048)
  __shared__ int lcur[NBK];
  __shared__ int sh[256];
  int t = threadIdx.x;
  int c = blockIdx.x;
  for (int i = t; i < 2048; i += 256) lh[i] = 0;
  __syncthreads();
  int base = c * EC;
  int end = min(E, base + EC);
  int cnt = end - base;
  for (int i = base + t; i < end; i += 256) atomicAdd(&lh[dst[i] >> BSH], 1);
  __syncthreads();
  // exclusive scan of lh[0..2047]
  int loc[8];
  int s = 0;
#pragma unroll
  for (int i = 0; i < 8; ++i) {
    loc[i] = lh[t * 8 + i];
    s += loc[i];
  }
  sh[t] = s;
  __syncthreads();
  for (int d = 1; d < 256; d <<= 1) {
    int a = (t >= d) ? sh[t - d] : 0;
    __syncthreads();
    sh[t] += a;
    __syncthreads();
  }
  int run = sh[t] - s;
#pragma unroll
  for (int i = 0; i < 8; ++i) {
    int v = loc[i];
    lh[t * 8 + i] = run;
    run += v;
  }
  __syncthreads();
  for (int i = t; i < NBK; i += 256) lcur[i] = lh[i];
  __syncthreads();
  // place edges into stage in bucket order
  for (int i = base + t; i < end; i += 256) {
    int d = dst[i];
    int b = d >> BSH;
    int pos = atomicAdd(&lcur[b], 1);
    stage[pos] = ((uint_t)(d & (BNODES - 1)) << 20) | (uint_t)src[i];
  }
  __syncthreads();
  // flat copy-out: binary search bucket of stage position i (lh[b] <= i < lh[b+1])
  for (int i = t; i < cnt; i += 256) {
    int lo = 0, hi = NBK;
    while (hi - lo > 1) {
      int mid = (lo + hi) >> 1;
      if (lh[mid] <= i) lo = mid; else hi = mid;
    }
    int gb = gmatS[(size_t)lo * B + c];
    parts[gb + (i - lh[lo])] = stage[i];
  }
}

// ---------------- bucket segment -> CSR (no sort needed) ----------------
// all edges of bucket b are exactly nodes [b*64, b*64+64); rp gives exact
// per-node offsets. Writes land in a contiguous ~4KB window (L2-local).

__global__ __launch_bounds__(256) void k_sort2(const uint_t* __restrict__ parts,
                                               const int* __restrict__ gmatS,
                                               const int* __restrict__ rp,
                                               int* __restrict__ csrc, int B, int n) {
  __shared__ int lcur[BNODES];
  int t = threadIdx.x;
  int b = blockIdx.x;
  if (t < BNODES) {
    int idx = (b << BSH) + t;
    lcur[t] = rp[min(idx, n)];
  }
  __syncthreads();
  int s0 = gmatS[(size_t)b * B];
  int s1 = gmatS[(size_t)(b + 1) * B];
  for (int i = s0 + t; i < s1; i += 256) {
    uint_t u = parts[i];
    int dl = u >> 20;
    int pos = atomicAdd(&lcur[dl], 1);
    csrc[pos] = (int)(u & 0xFFFFFu);
  }
}

// ---------------- fp32 -> bf16 convert ----------------

__global__ void k_cvt(const float* __restrict__ x, ushort_t* __restrict__ y, int total4) {
  int i = blockIdx.x * 256 + threadIdx.x;
  if (i < total4) {
    float4 v = *(const float4*)&x[i * 4];
    uint2 p;
    p.x = pack_bf16x2(v.x, v.y);
    p.y = pack_bf16x2(v.z, v.w);
    *(uint2*)&y[i * 4] = p;
  }
}

// ---------------- W pack: fp32 [K][128] -> bf16 MFMA B-frag order ----------------

__global__ void k_packw(const float* __restrict__ W, ushort_t* __restrict__ P) {
  int t = blockIdx.x * 256 + threadIdx.x;
  int lane = t & 63;
  int j = (t >> 6) & 7;
  int kk = t >> 9;
  int krow = kk * 32 + (lane >> 4) * 8;
  int col = j * 16 + (lane & 15);
  ushort_t o[8];
#pragma unroll
  for (int i = 0; i < 8; ++i) o[i] = bf16_rte(W[(size_t)(krow + i) * 128 + col]);
  uint4 v;
  v.x = (uint_t)o[0] | ((uint_t)o[1] << 16);
  v.y = (uint_t)o[2] | ((uint_t)o[3] << 16);
  v.z = (uint_t)o[4] | ((uint_t)o[5] << 16);
  v.w = (uint_t)o[6] | ((uint_t)o[7] << 16);
  *(uint4*)&P[(size_t)t * 8] = v;
}

// ---------------- bf16 MFMA GEMM ----------------

template <int KK, bool ENC>
__global__ __launch_bounds__(256) void k_gemm_mfma(const ushort_t* __restrict__ A,
                                                   const ushort_t* __restrict__ Wp,
                                                   const float* __restrict__ aux,
                                                   ushort_t* __restrict__ C, int n) {
  int lane = threadIdx.x & 63;
  int wid = threadIdx.x >> 6;
  int r0 = (blockIdx.x * 4 + wid) * 16;
  if (r0 >= n) return;
  int arow = r0 + (lane & 15);
  if (arow >= n) arow = n - 1;
  const ushort_t* aptr = A + (size_t)arow * (KK * 32) + (lane >> 4) * 8;

  f32x4 acc[8] = {};
#pragma unroll
  for (int kk = 0; kk < KK; ++kk) {
    short8v a = *(const short8v*)(aptr + kk * 32);
    const ushort_t* wp = Wp + ((size_t)(kk * 8) * 64 + lane) * 8;
#pragma unroll
    for (int j = 0; j < 8; ++j) {
      short8v b = *(const short8v*)(wp + (size_t)j * 512);
      acc[j] = __builtin_amdgcn_mfma_f32_16x16x32_bf16(a, b, acc[j], 0, 0, 0);
    }
  }
  int rbase = r0 + (lane >> 4) * 4;
  int colb = lane & 15;
  float bcol[8];
  if constexpr (ENC) {
#pragma unroll
    for (int j = 0; j < 8; ++j) bcol[j] = aux[j * 16 + colb];
  }
#pragma unroll
  for (int reg = 0; reg < 4; ++reg) {
    int row = rbase + reg;
    if (row < n) {
      if constexpr (ENC) {
#pragma unroll
        for (int j = 0; j < 8; ++j)
          C[(size_t)row * 128 + j * 16 + colb] = bf16_rte(fmaxf(acc[j][reg] + bcol[j], 0.f));
      } else {
        float s = aux[row];
#pragma unroll
        for (int j = 0; j < 8; ++j)
          C[(size_t)row * 128 + j * 16 + colb] = bf16_rte(acc[j][reg] * s);
      }
    }
  }
}

// ---------------- aggregation + bias + LayerNorm + ReLU (bf16 in/out) ----------------
// one wave per node; quarter-waves (16 lanes = full 128-ch row via uint4) process
// interleaved edges; unroll-4 -> 16 outstanding gathers per wave.

__global__ __launch_bounds__(256) void k_agg(const uint4* __restrict__ hw4,  // [n][16]
                                             const int* __restrict__ rp,
                                             const int* __restrict__ csrc,
                                             const float* __restrict__ dis,
                                             const float* __restrict__ bias,
                                             const float* __restrict__ g,
                                             const float* __restrict__ bln,
                                             uint4* __restrict__ out4, int n) {
  int lane = threadIdx.x & 63;
  int q = lane >> 4;     // quarter 0..3
  int cl = lane & 15;    // channels 8cl..8cl+7
  int node = blockIdx.x * 4 + (threadIdx.x >> 6);
  if (node >= n) return;
  int start = rp[node], end = rp[node + 1];
  float a0 = 0.f, a1 = 0.f, a2 = 0.f, a3 = 0.f, a4 = 0.f, a5 = 0.f, a6 = 0.f, a7 = 0.f;
  int e = start + q;
  for (; e + 12 < end; e += 16) {
    int s0 = csrc[e], s1 = csrc[e + 4], s2 = csrc[e + 8], s3 = csrc[e + 12];
    uint4 u = hw4[(size_t)s0 * 16 + cl];
    uint4 v = hw4[(size_t)s1 * 16 + cl];
    uint4 w = hw4[(size_t)s2 * 16 + cl];
    uint4 z = hw4[(size_t)s3 * 16 + cl];
    a0 += bf_lo(u.x); a1 += bf_hi(u.x); a2 += bf_lo(u.y); a3 += bf_hi(u.y);
    a4 += bf_lo(u.z); a5 += bf_hi(u.z); a6 += bf_lo(u.w); a7 += bf_hi(u.w);
    a0 += bf_lo(v.x); a1 += bf_hi(v.x); a2 += bf_lo(v.y); a3 += bf_hi(v.y);
    a4 += bf_lo(v.z); a5 += bf_hi(v.z); a6 += bf_lo(v.w); a7 += bf_hi(v.w);
    a0 += bf_lo(w.x); a1 += bf_hi(w.x); a2 += bf_lo(w.y); a3 += bf_hi(w.y);
    a4 += bf_lo(w.z); a5 += bf_hi(w.z); a6 += bf_lo(w.w); a7 += bf_hi(w.w);
    a0 += bf_lo(z.x); a1 += bf_hi(z.x); a2 += bf_lo(z.y); a3 += bf_hi(z.y);
    a4 += bf_lo(z.z); a5 += bf_hi(z.z); a6 += bf_lo(z.w); a7 += bf_hi(z.w);
  }
  for (; e < end; e += 4) {
    int s0 = csrc[e];
    uint4 u = hw4[(size_t)s0 * 16 + cl];
    a0 += bf_lo(u.x); a1 += bf_hi(u.x); a2 += bf_lo(u.y); a3 += bf_hi(u.y);
    a4 += bf_lo(u.z); a5 += bf_hi(u.z); a6 += bf_lo(u.w); a7 += bf_hi(u.w);
  }
  // combine the 4 quarters (each holds the same 8 channels for disjoint edges)
#pragma unroll
  for (int m = 16; m < 64; m <<= 1) {
    a0 += __shfl_xor(a0, m, 64); a1 += __shfl_xor(a1, m, 64);
    a2 += __shfl_xor(a2, m, 64); a3 += __shfl_xor(a3, m, 64);
    a4 += __shfl_xor(a4, m, 64); a5 += __shfl_xor(a5, m, 64);
    a6 += __shfl_xor(a6, m, 64); a7 += __shfl_xor(a7, m, 64);
  }
  // self loop (rows pre-scaled by dis[src]); then * dis[node] + bias
  uint4 us = hw4[(size_t)node * 16 + cl];
  a0 += bf_lo(us.x); a1 += bf_hi(us.x); a2 += bf_lo(us.y); a3 += bf_hi(us.y);
  a4 += bf_lo(us.z); a5 += bf_hi(us.z); a6 += bf_lo(us.w); a7 += bf_hi(us.w);
  float dn = dis[node];
  float4 b0 = *(const float4*)&bias[cl * 8];
  float4 b1 = *(const float4*)&bias[cl * 8 + 4];
  a0 = fmaf(a0, dn, b0.x); a1 = fmaf(a1, dn, b0.y);
  a2 = fmaf(a2, dn, b0.z); a3 = fmaf(a3, dn, b0.w);
  a4 = fmaf(a4, dn, b1.x); a5 = fmaf(a5, dn, b1.y);
  a6 = fmaf(a6, dn, b1.z); a7 = fmaf(a7, dn, b1.w);
  // LayerNorm over 128 channels: reduce within each 16-lane quarter
  float s1v = a0 + a1 + a2 + a3 + a4 + a5 + a6 + a7;
  float s2v = a0 * a0 + a1 * a1 + a2 * a2 + a3 * a3 +
              a4 * a4 + a5 * a5 + a6 * a6 + a7 * a7;
#pragma unroll
  for (int m = 1; m < 16; m <<= 1) {
    s1v += __shfl_xor(s1v, m, 64);
    s2v += __shfl_xor(s2v, m, 64);
  }
  float mean = s1v * (1.0f / 128.0f);
  float var = s2v * (1.0f / 128.0f) - mean * mean;
  float rstd = rsqrtf(var + LN_EPS);
  float4 g0 = *(const float4*)&g[cl * 8];
  float4 g1 = *(const float4*)&g[cl * 8 + 4];
  float4 l0 = *(const float4*)&bln[cl * 8];
  float4 l1 = *(const float4*)&bln[cl * 8 + 4];
  float y0 = fmaxf(fmaf((a0 - mean) * rstd, g0.x, l0.x), 0.f);
  float y1 = fmaxf(fmaf((a1 - mean) * rstd, g0.y, l0.y), 0.f);
  float y2 = fmaxf(fmaf((a2 - mean) * rstd, g0.z, l0.z), 0.f);
  float y3 = fmaxf(fmaf((a3 - mean) * rstd, g0.w, l0.w), 0.f);
  float y4 = fmaxf(fmaf((a4 - mean) * rstd, g1.x, l1.x), 0.f);
  float y5 = fmaxf(fmaf((a5 - mean) * rstd, g1.y, l1.y), 0.f);
  float y6 = fmaxf(fmaf((a6 - mean) * rstd, g1.z, l1.z), 0.f);
  float y7 = fmaxf(fmaf((a7 - mean) * rstd, g1.w, l1.w), 0.f);
  if (q == 0) {
    uint4 p;
    p.x = pack_bf16x2(y0, y1);
    p.y = pack_bf16x2(y2, y3);
    p.z = pack_bf16x2(y4, y5);
    p.w = pack_bf16x2(y6, y7);
    out4[(size_t)node * 16 + cl] = p;
  }
}

// ---------------- output head ----------------

__global__ __launch_bounds__(256) void k_out(const ushort_t* __restrict__ x1,
                                             const ushort_t* __restrict__ x2,
                                             const float* __restrict__ w,
                                             const float* __restrict__ b,
                                             float* __restrict__ out, int n) {
  __shared__ float wl[256 * 16];
  __shared__ float bl[16];
  int tid = threadIdx.x;
#pragma unroll
  for (int i = 0; i < 4; ++i) {
    int idx = (i * 256 + tid) * 4;
    *(float4*)&wl[idx] = *(const float4*)&w[idx];
  }
  if (tid < 16) bl[tid] = b[tid];
  __syncthreads();
  int node = blockIdx.x * 256 + tid;
  if (node >= n) return;
  float acc[16];
#pragma unroll
  for (int o = 0; o < 16; ++o) acc[o] = bl[o];

  const ushort_t* xr = x1 + (size_t)node * 128;
#pragma unroll 2
  for (int c = 0; c < 128; c += 8) {
    uint4 xv = *(const uint4*)&xr[c];
    float f0 = bf_lo(xv.x), f1 = bf_hi(xv.x), f2 = bf_lo(xv.y), f3 = bf_hi(xv.y);
    float f4 = bf_lo(xv.z), f5 = bf_hi(xv.z), f6 = bf_lo(xv.w), f7 = bf_hi(xv.w);
#pragma unroll
    for (int o = 0; o < 16; ++o) {
      acc[o] = fmaf(f0, wl[(c + 0) * 16 + o],
               fmaf(f1, wl[(c + 1) * 16 + o],
               fmaf(f2, wl[(c + 2) * 16 + o],
               fmaf(f3, wl[(c + 3) * 16 + o],
               fmaf(f4, wl[(c + 4) * 16 + o],
               fmaf(f5, wl[(c + 5) * 16 + o],
               fmaf(f6, wl[(c + 6) * 16 + o],
               fmaf(f7, wl[(c + 7) * 16 + o], acc[o]))))))));
    }
  }
  const ushort_t* xr2 = x2 + (size_t)node * 128;
#pragma unroll 2
  for (int c = 0; c < 128; c += 8) {
    uint4 xv = *(const uint4*)&xr2[c];
    float f0 = bf_lo(xv.x), f1 = bf_hi(xv.x), f2 = bf_lo(xv.y), f3 = bf_hi(xv.y);
    float f4 = bf_lo(xv.z), f5 = bf_hi(xv.z), f6 = bf_lo(xv.w), f7 = bf_hi(xv.w);
#pragma unroll
    for (int o = 0; o < 16; ++o) {
      acc[o] = fmaf(f0, wl[(128 + c + 0) * 16 + o],
               fmaf(f1, wl[(128 + c + 1) * 16 + o],
               fmaf(f2, wl[(128 + c + 2) * 16 + o],
               fmaf(f3, wl[(128 + c + 3) * 16 + o],
               fmaf(f4, wl[(128 + c + 4) * 16 + o],
               fmaf(f5, wl[(128 + c + 5) * 16 + o],
               fmaf(f6, wl[(128 + c + 6) * 16 + o],
               fmaf(f7, wl[(128 + c + 7) * 16 + o], acc[o]))))))));
    }
  }
#pragma unroll
  for (int o = 0; o < 4; ++o) {
    *(float4*)&out[(size_t)node * 16 + o * 4] =
        make_float4(acc[o * 4], acc[o * 4 + 1], acc[o * 4 + 2], acc[o * 4 + 3]);
  }
}

// ---------------- host ----------------

extern "C" void kernel_launch(void* const* d_in, const int* in_sizes, int n_in,
                              void* d_out, int out_size, void* d_ws, size_t ws_size,
                              hipStream_t stream) {
  const float* x = (const float*)d_in[0];
  const int* ei1 = (const int*)d_in[1];
  const int* ei2 = (const int*)d_in[2];
  const float* enc_w = (const float*)d_in[3];
  const float* enc_b = (const float*)d_in[4];
  const float* conv_w[3] = {(const float*)d_in[5], (const float*)d_in[9], (const float*)d_in[13]};
  const float* conv_b[3] = {(const float*)d_in[6], (const float*)d_in[10], (const float*)d_in[14]};
  const float* ln_g[3] = {(const float*)d_in[7], (const float*)d_in[11], (const float*)d_in[15]};
  const float* ln_b[3] = {(const float*)d_in[8], (const float*)d_in[12], (const float*)d_in[16]};
  const float* out_w = (const float*)d_in[17];
  const float* out_b = (const float*)d_in[18];
  float* out = (float*)d_out;

  const int N = NN;
  const int E = in_sizes[1] / 2;
  const int B = (E + EC - 1) / EC;       // partition chunks
  const int M = NBK * B;                 // histogram matrix size

  char* ws = (char*)d_ws;
  size_t off = 0;
  auto alloc = [&](size_t bytes) -> char* {
    char* p = ws + off;
    off += (bytes + 255) & ~(size_t)255;
    return p;
  };
  ushort_t* h0 = (ushort_t*)alloc((size_t)N * 128 * 2);
  ushort_t* hb = (ushort_t*)alloc((size_t)N * 128 * 2);
  ushort_t* p1 = (ushort_t*)alloc((size_t)N * 128 * 2);
  ushort_t* p2 = (ushort_t*)alloc((size_t)N * 128 * 2);
  ushort_t* xb = (ushort_t*)alloc((size_t)N * 64 * 2);
  ushort_t* wpk[3];
  for (int l = 0; l < 3; ++l) wpk[l] = (ushort_t*)alloc(2048 * 8 * 2);
  ushort_t* wpe = (ushort_t*)alloc(1024 * 8 * 2);

  struct G {
    int* deg; float* dis; int* rp; int* gmatC; int* gmatS; int* bsum;
    uint_t* parts; int* csrc; const int* src; const int* dst;
  } g[2];
  for (int i = 0; i < 2; ++i) {
    g[i].deg = (int*)alloc((size_t)N * 4);
    g[i].dis = (float*)alloc((size_t)N * 4);
    g[i].rp = (int*)alloc((size_t)(N + 1) * 4);
    g[i].gmatC = (int*)alloc((size_t)M * 4);
    g[i].gmatS = (int*)alloc((size_t)(M + 1) * 4);
    g[i].bsum = (int*)alloc(64 * 4);
    g[i].parts = (uint_t*)alloc((size_t)E * 4);
    g[i].csrc = (int*)alloc((size_t)E * 4);
  }
  g[0].src = ei1; g[0].dst = ei1 + E;
  g[1].src = ei2; g[1].dst = ei2 + E;

  int ge = (E + 255) / 256;
  int nScanN = (N + 8191) / 8192;
  int nScanM = (M + 8191) / 8192;
  for (int i = 0; i < 2; ++i) {
    hipMemsetAsync(g[i].deg, 0, (size_t)N * 4, stream);
    k_hist<<<ge, 256, 0, stream>>>(g[i].dst, g[i].deg, E);
    k_dis<<<(N + 255) / 256, 256, 0, stream>>>(g[i].deg, g[i].dis, N);
    // rp = exclusive scan of deg over N (+ rp[N]=E)
    k_scanA32<<<nScanN, 256, 0, stream>>>(g[i].deg, g[i].rp, g[i].bsum, N);
    k_scanB<<<1, 64, 0, stream>>>(g[i].bsum, nScanN);
    k_scanC32<<<(N + 1 + 255) / 256, 256, 0, stream>>>(g[i].rp, g[i].bsum, N, E);
    // bucket partition
    k_phist<<<B, 256, 0, stream>>>(g[i].dst, g[i].gmatC, E, B);
    k_scanA32<<<nScanM, 256, 0, stream>>>(g[i].gmatC, g[i].gmatS, g[i].bsum, M);
    k_scanB<<<1, 64, 0, stream>>>(g[i].bsum, nScanM);
    k_scanC32<<<(M + 1 + 255) / 256, 256, 0, stream>>>(g[i].gmatS, g[i].bsum, M, E);
    k_pscatter<<<B, 256, 0, stream>>>(g[i].src, g[i].dst, g[i].gmatS, g[i].parts, E, B);
    // bucket segments -> CSR (localized writes, no sort)
    k_sort2<<<NBK, 256, 0, stream>>>(g[i].parts, g[i].gmatS, g[i].rp, g[i].csrc, B, N);
  }

  for (int l = 0; l < 3; ++l) k_packw<<<8, 256, 0, stream>>>(conv_w[l], wpk[l]);
  k_packw<<<4, 256, 0, stream>>>(enc_w, wpe);
  k_cvt<<<(N * 64 / 4 + 255) / 256, 256, 0, stream>>>(x, xb, N * 64 / 4);

  int gb = (N + 63) / 64;
  // shared encoder -> h0
  k_gemm_mfma<2, true><<<gb, 256, 0, stream>>>(xb, wpe, enc_b, h0, N);

  // branch 1: h0 -> ... -> x1 in p1
  {
    const ushort_t* cur = h0;
    for (int l = 0; l < 3; ++l) {
      k_gemm_mfma<4, false><<<gb, 256, 0, stream>>>(cur, wpk[l], g[0].dis, hb, N);
      k_agg<<<(N + 3) / 4, 256, 0, stream>>>((const uint4*)hb, g[0].rp, g[0].csrc,
                                             g[0].dis, conv_b[l], ln_g[l], ln_b[l],
                                             (uint4*)p1, N);
      cur = p1;
    }
  }
  // branch 2: h0 -> ... -> x2 in p2
  {
    const ushort_t* cur = h0;
    for (int l = 0; l < 3; ++l) {
      k_gemm_mfma<4, false><<<gb, 256, 0, stream>>>(cur, wpk[l], g[1].dis, hb, N);
      k_agg<<<(N + 3) / 4, 256, 0, stream>>>((const uint4*)hb, g[1].rp, g[1].csrc,
                                             g[1].dis, conv_b[l], ln_g[l], ln_b[l],
                                             (uint4*)p2, N);
      cur = p2;
    }
  }

  k_out<<<(N + 255) / 256, 256, 0, stream>>>(p1, p2, out_w, out_b, out, N);
}

// Round 10
// 738.368 us; speedup vs baseline: 10.6138x; 1.2094x over previous
//
#include <hip/hip_runtime.h>

#define NN 100000
#define LN_EPS 1e-5f
#define BSH 6                       // 64 nodes per bucket
#define BNODES 64
#define NBK ((NN + 63) >> 6)        // 1563 buckets
#define EC 6144                     // edges per partition chunk

typedef unsigned int uint_t;
typedef unsigned short ushort_t;
typedef __attribute__((ext_vector_type(8))) short short8v;
typedef __attribute__((ext_vector_type(4))) float f32x4;

// ---- bf16 helpers ----
// Manual round-to-nearest-even pack ONLY. Lessons learned:
//  - HW v_cvt_pk_bf16_f32: rounding differs (round-8 regression).
//  - v_dot2_f32_bf16: non-IEEE truncated 3-way accumulation (round-9 regression).
// Accumulate with plain IEEE f32 adds; pack with 3-op software RNE.

__device__ __forceinline__ uint_t cvtpk(float a, float b) {
  uint_t ua = __float_as_uint(a);
  ua = (ua + 0x7FFFu + ((ua >> 16) & 1u)) >> 16;
  uint_t ub = __float_as_uint(b);
  ub = (ub + 0x7FFFu + ((ub >> 16) & 1u)) & 0xFFFF0000u;
  return ua | ub;
}
__device__ __forceinline__ ushort_t bf16_1(float x) {
  uint_t u = __float_as_uint(x);
  return (ushort_t)((u + 0x7FFFu + ((u >> 16) & 1u)) >> 16);
}
__device__ __forceinline__ float bf_lo(uint_t u) { return __uint_as_float(u << 16); }
__device__ __forceinline__ float bf_hi(uint_t u) { return __uint_as_float(u & 0xFFFF0000u); }

// ---------------- scan (8192 per block, 32 per thread) ----------------

__global__ __launch_bounds__(256) void k_scanA32(const int* in, int* out,
                                                 int* bsum, int n) {
  __shared__ int sh[256];
  int t = threadIdx.x;
  int base = blockIdx.x * 8192 + t * 32;
  int v[32];
  int s = 0;
#pragma unroll
  for (int i = 0; i < 32; ++i) {
    int idx = base + i;
    v[i] = (idx < n) ? in[idx] : 0;
    s += v[i];
  }
  sh[t] = s;
  __syncthreads();
  for (int d = 1; d < 256; d <<= 1) {
    int a = (t >= d) ? sh[t - d] : 0;
    __syncthreads();
    sh[t] += a;
    __syncthreads();
  }
  int run = sh[t] - s;
  if (t == 255) bsum[blockIdx.x] = sh[255];
#pragma unroll
  for (int i = 0; i < 32; ++i) {
    int idx = base + i;
    if (idx < n) out[idx] = run;
    run += v[i];
  }
}

__global__ void k_scanB(int* bsum, int nb) {
  int t = threadIdx.x;
  int x = (t < nb) ? bsum[t] : 0;
  int incl = x;
#pragma unroll
  for (int d = 1; d < 64; d <<= 1) {
    int y = __shfl_up(incl, d, 64);
    if (t >= d) incl += y;
  }
  if (t < nb) bsum[t] = incl - x;
}

__global__ void k_scanC32(int* __restrict__ rp, const int* __restrict__ bsum,
                          int n, int total) {
  int i = blockIdx.x * 256 + threadIdx.x;
  if (i < n) rp[i] += bsum[i >> 13];
  else if (i == n) rp[n] = total;
}

// ---------------- partition: per-chunk histogram over buckets ----------------

__global__ __launch_bounds__(256) void k_phist(const int* __restrict__ dst,
                                               int* __restrict__ gmatC, int E, int B) {
  __shared__ int lh[NBK];
  int t = threadIdx.x;
  for (int i = t; i < NBK; i += 256) lh[i] = 0;
  __syncthreads();
  int base = blockIdx.x * EC;
  int end = min(E, base + EC);
  for (int i = base + t; i < end; i += 256) atomicAdd(&lh[dst[i] >> BSH], 1);
  __syncthreads();
  for (int b = t; b < NBK; b += 256) gmatC[(size_t)b * B + blockIdx.x] = lh[b];
}

// LDS counting sort of one chunk; flat copy-out via binary search -> coalesced.
// parts[pos] = (dst&63)<<20 | src
__global__ __launch_bounds__(256) void k_pscatter(const int* __restrict__ src,
                                                  const int* __restrict__ dst,
                                                  const int* __restrict__ gmatS,
                                                  uint_t* __restrict__ parts,
                                                  int E, int B) {
  __shared__ uint_t stage[EC];   // 24 KB
  __shared__ int lh[2048];
  __shared__ int lcur[NBK];
  __shared__ int sh[256];
  int t = threadIdx.x;
  int c = blockIdx.x;
  for (int i = t; i < 2048; i += 256) lh[i] = 0;
  __syncthreads();
  int base = c * EC;
  int end = min(E, base + EC);
  int cnt = end - base;
  for (int i = base + t; i < end; i += 256) atomicAdd(&lh[dst[i] >> BSH], 1);
  __syncthreads();
  int loc[8];
  int s = 0;
#pragma unroll
  for (int i = 0; i < 8; ++i) {
    loc[i] = lh[t * 8 + i];
    s += loc[i];
  }
  sh[t] = s;
  __syncthreads();
  for (int d = 1; d < 256; d <<= 1) {
    int a = (t >= d) ? sh[t - d] : 0;
    __syncthreads();
    sh[t] += a;
    __syncthreads();
  }
  int run = sh[t] - s;
#pragma unroll
  for (int i = 0; i < 8; ++i) {
    int v = loc[i];
    lh[t * 8 + i] = run;
    run += v;
  }
  __syncthreads();
  for (int i = t; i < NBK; i += 256) lcur[i] = lh[i];
  __syncthreads();
  for (int i = base + t; i < end; i += 256) {
    int d = dst[i];
    int b = d >> BSH;
    int pos = atomicAdd(&lcur[b], 1);
    stage[pos] = ((uint_t)(d & (BNODES - 1)) << 20) | (uint_t)src[i];
  }
  __syncthreads();
  for (int i = t; i < cnt; i += 256) {
    int lo = 0, hi = NBK;
    while (hi - lo > 1) {
      int mid = (lo + hi) >> 1;
      if (lh[mid] <= i) lo = mid; else hi = mid;
    }
    int gb = gmatS[(size_t)lo * B + c];
    parts[gb + (i - lh[lo])] = stage[i];
  }
}

// ---------------- per-bucket degree count + dis ----------------

__global__ __launch_bounds__(256) void k_degb(const uint_t* __restrict__ parts,
                                              const int* __restrict__ gmatS,
                                              int* __restrict__ deg,
                                              float* __restrict__ dis, int B, int n) {
  __shared__ int cnt[BNODES];
  int t = threadIdx.x;
  int b = blockIdx.x;
  if (t < BNODES) cnt[t] = 0;
  __syncthreads();
  int s0 = gmatS[(size_t)b * B];
  int s1 = gmatS[(size_t)(b + 1) * B];
  for (int i = s0 + t; i < s1; i += 256) atomicAdd(&cnt[parts[i] >> 20], 1);
  __syncthreads();
  if (t < BNODES) {
    int node = (b << BSH) + t;
    if (node < n) {
      int c = cnt[t];
      deg[node] = c;
      dis[node] = rsqrtf((float)(c + 1));
    }
  }
}

// ---------------- bucket segment -> CSR (csrc holds BYTE offsets src*256) ------

__global__ __launch_bounds__(256) void k_sort2(const uint_t* __restrict__ parts,
                                               const int* __restrict__ gmatS,
                                               const int* __restrict__ rp,
                                               int* __restrict__ csrc, int B, int n) {
  __shared__ int lcur[BNODES];
  int t = threadIdx.x;
  int b = blockIdx.x;
  if (t < BNODES) {
    int idx = (b << BSH) + t;
    lcur[t] = rp[min(idx, n)];
  }
  __syncthreads();
  int s0 = gmatS[(size_t)b * B];
  int s1 = gmatS[(size_t)(b + 1) * B];
  for (int i = s0 + t; i < s1; i += 256) {
    uint_t u = parts[i];
    int dl = u >> 20;
    int pos = atomicAdd(&lcur[dl], 1);
    csrc[pos] = (int)((u & 0xFFFFFu) << 8);   // byte offset of the 256B row
  }
}

// ---------------- fp32 -> bf16 convert ----------------

__global__ void k_cvt(const float* __restrict__ x, ushort_t* __restrict__ y, int total4) {
  int i = blockIdx.x * 256 + threadIdx.x;
  if (i < total4) {
    float4 v = *(const float4*)&x[i * 4];
    uint2 p;
    p.x = cvtpk(v.x, v.y);
    p.y = cvtpk(v.z, v.w);
    *(uint2*)&y[i * 4] = p;
  }
}

// ---------------- W pack: fp32 [K][128] -> bf16 MFMA B-frag order ----------------

__global__ void k_packw(const float* __restrict__ W, ushort_t* __restrict__ P) {
  int t = blockIdx.x * 256 + threadIdx.x;
  int lane = t & 63;
  int j = (t >> 6) & 7;
  int kk = t >> 9;
  int krow = kk * 32 + (lane >> 4) * 8;
  int col = j * 16 + (lane & 15);
  uint4 v;
  v.x = cvtpk(W[(size_t)(krow + 0) * 128 + col], W[(size_t)(krow + 1) * 128 + col]);
  v.y = cvtpk(W[(size_t)(krow + 2) * 128 + col], W[(size_t)(krow + 3) * 128 + col]);
  v.z = cvtpk(W[(size_t)(krow + 4) * 128 + col], W[(size_t)(krow + 5) * 128 + col]);
  v.w = cvtpk(W[(size_t)(krow + 6) * 128 + col], W[(size_t)(krow + 7) * 128 + col]);
  *(uint4*)&P[(size_t)t * 8] = v;
}

// ---------------- bf16 MFMA GEMM ----------------

template <int KK, bool ENC>
__global__ __launch_bounds__(256) void k_gemm_mfma(const ushort_t* __restrict__ A,
                                                   const ushort_t* __restrict__ Wp,
                                                   const float* __restrict__ aux,
                                                   ushort_t* __restrict__ C, int n) {
  int lane = threadIdx.x & 63;
  int wid = threadIdx.x >> 6;
  int r0 = (blockIdx.x * 4 + wid) * 16;
  if (r0 >= n) return;
  int arow = r0 + (lane & 15);
  if (arow >= n) arow = n - 1;
  const ushort_t* aptr = A + (size_t)arow * (KK * 32) + (lane >> 4) * 8;

  f32x4 acc[8] = {};
#pragma unroll
  for (int kk = 0; kk < KK; ++kk) {
    short8v a = *(const short8v*)(aptr + kk * 32);
    const ushort_t* wp = Wp + ((size_t)(kk * 8) * 64 + lane) * 8;
#pragma unroll
    for (int j = 0; j < 8; ++j) {
      short8v b = *(const short8v*)(wp + (size_t)j * 512);
      acc[j] = __builtin_amdgcn_mfma_f32_16x16x32_bf16(a, b, acc[j], 0, 0, 0);
    }
  }
  int rbase = r0 + (lane >> 4) * 4;
  int colb = lane & 15;
  float bcol[8];
  if constexpr (ENC) {
#pragma unroll
    for (int j = 0; j < 8; ++j) bcol[j] = aux[j * 16 + colb];
  }
#pragma unroll
  for (int reg = 0; reg < 4; ++reg) {
    int row = rbase + reg;
    if (row < n) {
      if constexpr (ENC) {
#pragma unroll
        for (int j = 0; j < 8; ++j)
          C[(size_t)row * 128 + j * 16 + colb] = bf16_1(fmaxf(acc[j][reg] + bcol[j], 0.f));
      } else {
        float s = aux[row];
#pragma unroll
        for (int j = 0; j < 8; ++j)
          C[(size_t)row * 128 + j * 16 + colb] = bf16_1(acc[j][reg] * s);
      }
    }
  }
}

// dual-output variant for layer 0 (same MFMA, two dis scalings)
__global__ __launch_bounds__(256) void k_gemm_mfma2(const ushort_t* __restrict__ A,
                                                    const ushort_t* __restrict__ Wp,
                                                    const float* __restrict__ dis1,
                                                    const float* __restrict__ dis2,
                                                    ushort_t* __restrict__ C1,
                                                    ushort_t* __restrict__ C2, int n) {
  int lane = threadIdx.x & 63;
  int wid = threadIdx.x >> 6;
  int r0 = (blockIdx.x * 4 + wid) * 16;
  if (r0 >= n) return;
  int arow = r0 + (lane & 15);
  if (arow >= n) arow = n - 1;
  const ushort_t* aptr = A + (size_t)arow * 128 + (lane >> 4) * 8;

  f32x4 acc[8] = {};
#pragma unroll
  for (int kk = 0; kk < 4; ++kk) {
    short8v a = *(const short8v*)(aptr + kk * 32);
    const ushort_t* wp = Wp + ((size_t)(kk * 8) * 64 + lane) * 8;
#pragma unroll
    for (int j = 0; j < 8; ++j) {
      short8v b = *(const short8v*)(wp + (size_t)j * 512);
      acc[j] = __builtin_amdgcn_mfma_f32_16x16x32_bf16(a, b, acc[j], 0, 0, 0);
    }
  }
  int rbase = r0 + (lane >> 4) * 4;
  int colb = lane & 15;
#pragma unroll
  for (int reg = 0; reg < 4; ++reg) {
    int row = rbase + reg;
    if (row < n) {
      float s1 = dis1[row];
      float s2 = dis2[row];
#pragma unroll
      for (int j = 0; j < 8; ++j) {
        float v = acc[j][reg];
        C1[(size_t)row * 128 + j * 16 + colb] = bf16_1(v * s1);
        C2[(size_t)row * 128 + j * 16 + colb] = bf16_1(v * s2);
      }
    }
  }
}

// ---------------- aggregation + bias + LayerNorm + ReLU (bf16 in/out) ----------------
// one wave per node; quarter-waves (16 lanes x 16B = full 128-ch row); unroll-4;
// explicit unpack + IEEE f32 adds (round-7 proven numerics).

#define ACC8(U)                                                   \
  a0 += bf_lo(U.x); a1 += bf_hi(U.x); a2 += bf_lo(U.y); a3 += bf_hi(U.y); \
  a4 += bf_lo(U.z); a5 += bf_hi(U.z); a6 += bf_lo(U.w); a7 += bf_hi(U.w);

__global__ __launch_bounds__(256) void k_agg(const char* __restrict__ hwb,  // [n] 256B rows
                                             const int* __restrict__ rp,
                                             const int* __restrict__ csrc,  // byte offsets
                                             const float* __restrict__ dis,
                                             const float* __restrict__ bias,
                                             const float* __restrict__ g,
                                             const float* __restrict__ bln,
                                             uint4* __restrict__ out4, int n) {
  int lane = threadIdx.x & 63;
  int q = lane >> 4;
  int cl = lane & 15;
  int clOff = cl << 4;
  int node = blockIdx.x * 4 + (threadIdx.x >> 6);
  if (node >= n) return;
  int start = rp[node], end = rp[node + 1];
  float a0 = 0.f, a1 = 0.f, a2 = 0.f, a3 = 0.f, a4 = 0.f, a5 = 0.f, a6 = 0.f, a7 = 0.f;
  int e = start + q;
  for (; e + 12 < end; e += 16) {
    int o0 = csrc[e] + clOff;
    int o1 = csrc[e + 4] + clOff;
    int o2 = csrc[e + 8] + clOff;
    int o3 = csrc[e + 12] + clOff;
    uint4 u = *(const uint4*)(hwb + o0);
    uint4 v = *(const uint4*)(hwb + o1);
    uint4 w = *(const uint4*)(hwb + o2);
    uint4 z = *(const uint4*)(hwb + o3);
    ACC8(u); ACC8(v); ACC8(w); ACC8(z);
  }
  for (; e < end; e += 4) {
    int o0 = csrc[e] + clOff;
    uint4 u = *(const uint4*)(hwb + o0);
    ACC8(u);
  }
  // combine the 4 quarters
#pragma unroll
  for (int m = 16; m < 64; m <<= 1) {
    a0 += __shfl_xor(a0, m, 64); a1 += __shfl_xor(a1, m, 64);
    a2 += __shfl_xor(a2, m, 64); a3 += __shfl_xor(a3, m, 64);
    a4 += __shfl_xor(a4, m, 64); a5 += __shfl_xor(a5, m, 64);
    a6 += __shfl_xor(a6, m, 64); a7 += __shfl_xor(a7, m, 64);
  }
  // self loop (rows pre-scaled by dis[src]); then * dis[node] + bias
  uint4 us = *(const uint4*)(hwb + node * 256 + clOff);
  ACC8(us);
  float dn = dis[node];
  float4 b0 = *(const float4*)&bias[cl * 8];
  float4 b1 = *(const float4*)&bias[cl * 8 + 4];
  a0 = fmaf(a0, dn, b0.x); a1 = fmaf(a1, dn, b0.y);
  a2 = fmaf(a2, dn, b0.z); a3 = fmaf(a3, dn, b0.w);
  a4 = fmaf(a4, dn, b1.x); a5 = fmaf(a5, dn, b1.y);
  a6 = fmaf(a6, dn, b1.z); a7 = fmaf(a7, dn, b1.w);
  // LayerNorm over 128 channels (reduce within 16-lane quarter)
  float s1v = a0 + a1 + a2 + a3 + a4 + a5 + a6 + a7;
  float s2v = a0 * a0 + a1 * a1 + a2 * a2 + a3 * a3 +
              a4 * a4 + a5 * a5 + a6 * a6 + a7 * a7;
#pragma unroll
  for (int m = 1; m < 16; m <<= 1) {
    s1v += __shfl_xor(s1v, m, 64);
    s2v += __shfl_xor(s2v, m, 64);
  }
  float mean = s1v * (1.0f / 128.0f);
  float var = s2v * (1.0f / 128.0f) - mean * mean;
  float rstd = rsqrtf(var + LN_EPS);
  float4 g0 = *(const float4*)&g[cl * 8];
  float4 g1 = *(const float4*)&g[cl * 8 + 4];
  float4 l0 = *(const float4*)&bln[cl * 8];
  float4 l1 = *(const float4*)&bln[cl * 8 + 4];
  float y0 = fmaxf(fmaf((a0 - mean) * rstd, g0.x, l0.x), 0.f);
  float y1 = fmaxf(fmaf((a1 - mean) * rstd, g0.y, l0.y), 0.f);
  float y2 = fmaxf(fmaf((a2 - mean) * rstd, g0.z, l0.z), 0.f);
  float y3 = fmaxf(fmaf((a3 - mean) * rstd, g0.w, l0.w), 0.f);
  float y4 = fmaxf(fmaf((a4 - mean) * rstd, g1.x, l1.x), 0.f);
  float y5 = fmaxf(fmaf((a5 - mean) * rstd, g1.y, l1.y), 0.f);
  float y6 = fmaxf(fmaf((a6 - mean) * rstd, g1.z, l1.z), 0.f);
  float y7 = fmaxf(fmaf((a7 - mean) * rstd, g1.w, l1.w), 0.f);
  if (q == 0) {
    uint4 p;
    p.x = cvtpk(y0, y1);
    p.y = cvtpk(y2, y3);
    p.z = cvtpk(y4, y5);
    p.w = cvtpk(y6, y7);
    out4[(size_t)node * 16 + cl] = p;
  }
}

// ---------------- output head ----------------

__global__ __launch_bounds__(256) void k_out(const ushort_t* __restrict__ x1,
                                             const ushort_t* __restrict__ x2,
                                             const float* __restrict__ w,
                                             const float* __restrict__ b,
                                             float* __restrict__ out, int n) {
  __shared__ float wl[256 * 16];
  __shared__ float bl[16];
  int tid = threadIdx.x;
#pragma unroll
  for (int i = 0; i < 4; ++i) {
    int idx = (i * 256 + tid) * 4;
    *(float4*)&wl[idx] = *(const float4*)&w[idx];
  }
  if (tid < 16) bl[tid] = b[tid];
  __syncthreads();
  int node = blockIdx.x * 256 + tid;
  if (node >= n) return;
  float acc[16];
#pragma unroll
  for (int o = 0; o < 16; ++o) acc[o] = bl[o];

  const ushort_t* xr = x1 + (size_t)node * 128;
#pragma unroll 2
  for (int c = 0; c < 128; c += 8) {
    uint4 xv = *(const uint4*)&xr[c];
    float f0 = bf_lo(xv.x), f1 = bf_hi(xv.x), f2 = bf_lo(xv.y), f3 = bf_hi(xv.y);
    float f4 = bf_lo(xv.z), f5 = bf_hi(xv.z), f6 = bf_lo(xv.w), f7 = bf_hi(xv.w);
#pragma unroll
    for (int o = 0; o < 16; ++o) {
      acc[o] = fmaf(f0, wl[(c + 0) * 16 + o],
               fmaf(f1, wl[(c + 1) * 16 + o],
               fmaf(f2, wl[(c + 2) * 16 + o],
               fmaf(f3, wl[(c + 3) * 16 + o],
               fmaf(f4, wl[(c + 4) * 16 + o],
               fmaf(f5, wl[(c + 5) * 16 + o],
               fmaf(f6, wl[(c + 6) * 16 + o],
               fmaf(f7, wl[(c + 7) * 16 + o], acc[o]))))))));
    }
  }
  const ushort_t* xr2 = x2 + (size_t)node * 128;
#pragma unroll 2
  for (int c = 0; c < 128; c += 8) {
    uint4 xv = *(const uint4*)&xr2[c];
    float f0 = bf_lo(xv.x), f1 = bf_hi(xv.x), f2 = bf_lo(xv.y), f3 = bf_hi(xv.y);
    float f4 = bf_lo(xv.z), f5 = bf_hi(xv.z), f6 = bf_lo(xv.w), f7 = bf_hi(xv.w);
#pragma unroll
    for (int o = 0; o < 16; ++o) {
      acc[o] = fmaf(f0, wl[(128 + c + 0) * 16 + o],
               fmaf(f1, wl[(128 + c + 1) * 16 + o],
               fmaf(f2, wl[(128 + c + 2) * 16 + o],
               fmaf(f3, wl[(128 + c + 3) * 16 + o],
               fmaf(f4, wl[(128 + c + 4) * 16 + o],
               fmaf(f5, wl[(128 + c + 5) * 16 + o],
               fmaf(f6, wl[(128 + c + 6) * 16 + o],
               fmaf(f7, wl[(128 + c + 7) * 16 + o], acc[o]))))))));
    }
  }
#pragma unroll
  for (int o = 0; o < 4; ++o) {
    *(float4*)&out[(size_t)node * 16 + o * 4] =
        make_float4(acc[o * 4], acc[o * 4 + 1], acc[o * 4 + 2], acc[o * 4 + 3]);
  }
}

// ---------------- host ----------------

extern "C" void kernel_launch(void* const* d_in, const int* in_sizes, int n_in,
                              void* d_out, int out_size, void* d_ws, size_t ws_size,
                              hipStream_t stream) {
  const float* x = (const float*)d_in[0];
  const int* ei1 = (const int*)d_in[1];
  const int* ei2 = (const int*)d_in[2];
  const float* enc_w = (const float*)d_in[3];
  const float* enc_b = (const float*)d_in[4];
  const float* conv_w[3] = {(const float*)d_in[5], (const float*)d_in[9], (const float*)d_in[13]};
  const float* conv_b[3] = {(const float*)d_in[6], (const float*)d_in[10], (const float*)d_in[14]};
  const float* ln_g[3] = {(const float*)d_in[7], (const float*)d_in[11], (const float*)d_in[15]};
  const float* ln_b[3] = {(const float*)d_in[8], (const float*)d_in[12], (const float*)d_in[16]};
  const float* out_w = (const float*)d_in[17];
  const float* out_b = (const float*)d_in[18];
  float* out = (float*)d_out;

  const int N = NN;
  const int E = in_sizes[1] / 2;
  const int B = (E + EC - 1) / EC;       // partition chunks
  const int M = NBK * B;                 // histogram matrix size

  char* ws = (char*)d_ws;
  size_t off = 0;
  auto alloc = [&](size_t bytes) -> char* {
    char* p = ws + off;
    off += (bytes + 255) & ~(size_t)255;
    return p;
  };
  ushort_t* h0 = (ushort_t*)alloc((size_t)N * 128 * 2);
  ushort_t* hb = (ushort_t*)alloc((size_t)N * 128 * 2);
  ushort_t* hb2 = (ushort_t*)alloc((size_t)N * 128 * 2);
  ushort_t* p1 = (ushort_t*)alloc((size_t)N * 128 * 2);
  ushort_t* p2 = (ushort_t*)alloc((size_t)N * 128 * 2);
  ushort_t* xb = (ushort_t*)alloc((size_t)N * 64 * 2);
  ushort_t* wpk[3];
  for (int l = 0; l < 3; ++l) wpk[l] = (ushort_t*)alloc(2048 * 8 * 2);
  ushort_t* wpe = (ushort_t*)alloc(1024 * 8 * 2);

  struct G {
    int* deg; float* dis; int* rp; int* gmatC; int* gmatS; int* bsum;
    uint_t* parts; int* csrc; const int* src; const int* dst;
  } g[2];
  for (int i = 0; i < 2; ++i) {
    g[i].deg = (int*)alloc((size_t)N * 4);
    g[i].dis = (float*)alloc((size_t)N * 4);
    g[i].rp = (int*)alloc((size_t)(N + 1) * 4);
    g[i].gmatC = (int*)alloc((size_t)M * 4);
    g[i].gmatS = (int*)alloc((size_t)(M + 1) * 4);
    g[i].bsum = (int*)alloc(64 * 4);
    g[i].parts = (uint_t*)alloc((size_t)E * 4);
    g[i].csrc = (int*)alloc((size_t)E * 4);
  }
  g[0].src = ei1; g[0].dst = ei1 + E;
  g[1].src = ei2; g[1].dst = ei2 + E;

  int nScanN = (N + 8191) / 8192;
  int nScanM = (M + 8191) / 8192;
  for (int i = 0; i < 2; ++i) {
    // bucket partition
    k_phist<<<B, 256, 0, stream>>>(g[i].dst, g[i].gmatC, E, B);
    k_scanA32<<<nScanM, 256, 0, stream>>>(g[i].gmatC, g[i].gmatS, g[i].bsum, M);
    k_scanB<<<1, 64, 0, stream>>>(g[i].bsum, nScanM);
    k_scanC32<<<(M + 1 + 255) / 256, 256, 0, stream>>>(g[i].gmatS, g[i].bsum, M, E);
    k_pscatter<<<B, 256, 0, stream>>>(g[i].src, g[i].dst, g[i].gmatS, g[i].parts, E, B);
    // degree + dis from partitioned edges (LDS counters)
    k_degb<<<NBK, 256, 0, stream>>>(g[i].parts, g[i].gmatS, g[i].deg, g[i].dis, B, N);
    // rp = exclusive scan of deg
    k_scanA32<<<nScanN, 256, 0, stream>>>(g[i].deg, g[i].rp, g[i].bsum, N);
    k_scanB<<<1, 64, 0, stream>>>(g[i].bsum, nScanN);
    k_scanC32<<<(N + 1 + 255) / 256, 256, 0, stream>>>(g[i].rp, g[i].bsum, N, E);
    // bucket segments -> CSR (byte offsets)
    k_sort2<<<NBK, 256, 0, stream>>>(g[i].parts, g[i].gmatS, g[i].rp, g[i].csrc, B, N);
  }

  for (int l = 0; l < 3; ++l) k_packw<<<8, 256, 0, stream>>>(conv_w[l], wpk[l]);
  k_packw<<<4, 256, 0, stream>>>(enc_w, wpe);
  k_cvt<<<(N * 64 / 4 + 255) / 256, 256, 0, stream>>>(x, xb, N * 64 / 4);

  int gb = (N + 63) / 64;
  // shared encoder -> h0
  k_gemm_mfma<2, true><<<gb, 256, 0, stream>>>(xb, wpe, enc_b, h0, N);

  // layer 0 (shared GEMM, two dis scalings)
  k_gemm_mfma2<<<gb, 256, 0, stream>>>(h0, wpk[0], g[0].dis, g[1].dis, hb, hb2, N);
  k_agg<<<(N + 3) / 4, 256, 0, stream>>>((const char*)hb, g[0].rp, g[0].csrc,
                                         g[0].dis, conv_b[0], ln_g[0], ln_b[0],
                                         (uint4*)p1, N);
  k_agg<<<(N + 3) / 4, 256, 0, stream>>>((const char*)hb2, g[1].rp, g[1].csrc,
                                         g[1].dis, conv_b[0], ln_g[0], ln_b[0],
                                         (uint4*)p2, N);
  // branch 1: layers 1,2
  for (int l = 1; l < 3; ++l) {
    k_gemm_mfma<4, false><<<gb, 256, 0, stream>>>(p1, wpk[l], g[0].dis, hb, N);
    k_agg<<<(N + 3) / 4, 256, 0, stream>>>((const char*)hb, g[0].rp, g[0].csrc,
                                           g[0].dis, conv_b[l], ln_g[l], ln_b[l],
                                           (uint4*)p1, N);
  }
  // branch 2: layers 1,2
  for (int l = 1; l < 3; ++l) {
    k_gemm_mfma<4, false><<<gb, 256, 0, stream>>>(p2, wpk[l], g[1].dis, hb2, N);
    k_agg<<<(N + 3) / 4, 256, 0, stream>>>((const char*)hb2, g[1].rp, g[1].csrc,
                                           g[1].dis, conv_b[l], ln_g[l], ln_b[l],
                                           (uint4*)p2, N);
  }

  k_out<<<(N + 255) / 256, 256, 0, stream>>>(p1, p2, out_w, out_b, out, N);
}

// Round 11
// 626.440 us; speedup vs baseline: 12.5101x; 1.1787x over previous
//
#include <hip/hip_runtime.h>

#define NN 100000
#define LN_EPS 1e-5f
#define BSH 6                       // 64 nodes per bucket
#define BNODES 64
#define NBK ((NN + 63) >> 6)        // 1563 buckets
#define EC 6144                     // edges per partition chunk

typedef unsigned int uint_t;
typedef unsigned short ushort_t;
typedef __attribute__((ext_vector_type(8))) short short8v;
typedef __attribute__((ext_vector_type(4))) float f32x4;

// ---- bf16 helpers ----
// Manual RNE pack ONLY (HW cvt_pk rounds differently: r8; dot2 truncates: r9).

__device__ __forceinline__ uint_t cvtpk(float a, float b) {
  uint_t ua = __float_as_uint(a);
  ua = (ua + 0x7FFFu + ((ua >> 16) & 1u)) >> 16;
  uint_t ub = __float_as_uint(b);
  ub = (ub + 0x7FFFu + ((ub >> 16) & 1u)) & 0xFFFF0000u;
  return ua | ub;
}
__device__ __forceinline__ ushort_t bf16_1(float x) {
  uint_t u = __float_as_uint(x);
  return (ushort_t)((u + 0x7FFFu + ((u >> 16) & 1u)) >> 16);
}
__device__ __forceinline__ float bf_lo(uint_t u) { return __uint_as_float(u << 16); }
__device__ __forceinline__ float bf_hi(uint_t u) { return __uint_as_float(u & 0xFFFF0000u); }

// ---------------- scan over gmat matrices (both graphs via blockIdx.y) ------

__global__ __launch_bounds__(256) void k_scanA32(const int* in0, const int* in1,
                                                 int* out0, int* out1,
                                                 int* bsum0, int* bsum1, int n) {
  const int* in = blockIdx.y ? in1 : in0;
  int* out = blockIdx.y ? out1 : out0;
  int* bsum = blockIdx.y ? bsum1 : bsum0;
  __shared__ int sh[256];
  int t = threadIdx.x;
  int base = blockIdx.x * 8192 + t * 32;
  int v[32];
  int s = 0;
#pragma unroll
  for (int i = 0; i < 32; ++i) {
    int idx = base + i;
    v[i] = (idx < n) ? in[idx] : 0;
    s += v[i];
  }
  sh[t] = s;
  __syncthreads();
  for (int d = 1; d < 256; d <<= 1) {
    int a = (t >= d) ? sh[t - d] : 0;
    __syncthreads();
    sh[t] += a;
    __syncthreads();
  }
  int run = sh[t] - s;
  if (t == 255) bsum[blockIdx.x] = sh[255];
#pragma unroll
  for (int i = 0; i < 32; ++i) {
    int idx = base + i;
    if (idx < n) out[idx] = run;
    run += v[i];
  }
}

__global__ void k_scanB(int* bsum0, int* bsum1, int nb) {
  int* bsum = blockIdx.y ? bsum1 : bsum0;
  int t = threadIdx.x;
  int x = (t < nb) ? bsum[t] : 0;
  int incl = x;
#pragma unroll
  for (int d = 1; d < 64; d <<= 1) {
    int y = __shfl_up(incl, d, 64);
    if (t >= d) incl += y;
  }
  if (t < nb) bsum[t] = incl - x;
}

__global__ void k_scanC32(int* rp0, int* rp1, const int* bsum0, const int* bsum1,
                          int n, int total) {
  int* rp = blockIdx.y ? rp1 : rp0;
  const int* bsum = blockIdx.y ? bsum1 : bsum0;
  int i = blockIdx.x * 256 + threadIdx.x;
  if (i < n) rp[i] += bsum[i >> 13];
  else if (i == n) rp[n] = total;
}

// ---------------- partition: per-chunk histogram over buckets (both graphs) --

__global__ __launch_bounds__(256) void k_phist(const int* dst0, const int* dst1,
                                               int* gmatC0, int* gmatC1, int E, int B) {
  const int* dst = blockIdx.y ? dst1 : dst0;
  int* gmatC = blockIdx.y ? gmatC1 : gmatC0;
  __shared__ int lh[NBK];
  int t = threadIdx.x;
  for (int i = t; i < NBK; i += 256) lh[i] = 0;
  __syncthreads();
  int base = blockIdx.x * EC;
  int end = min(E, base + EC);
  for (int i = base + t; i < end; i += 256) atomicAdd(&lh[dst[i] >> BSH], 1);
  __syncthreads();
  for (int b = t; b < NBK; b += 256) gmatC[(size_t)b * B + blockIdx.x] = lh[b];
}

// LDS counting sort of one chunk; flat copy-out via binary search (both graphs).
// parts[pos] = (dst&63)<<20 | src
__global__ __launch_bounds__(256) void k_pscatter(const int* src0, const int* src1,
                                                  const int* dst0, const int* dst1,
                                                  const int* gmatS0, const int* gmatS1,
                                                  uint_t* parts0, uint_t* parts1,
                                                  int E, int B) {
  const int* src = blockIdx.y ? src1 : src0;
  const int* dst = blockIdx.y ? dst1 : dst0;
  const int* gmatS = blockIdx.y ? gmatS1 : gmatS0;
  uint_t* parts = blockIdx.y ? parts1 : parts0;
  __shared__ uint_t stage[EC];   // 24 KB
  __shared__ int lh[2048];
  __shared__ int lcur[NBK];
  __shared__ int sh[256];
  int t = threadIdx.x;
  int c = blockIdx.x;
  for (int i = t; i < 2048; i += 256) lh[i] = 0;
  __syncthreads();
  int base = c * EC;
  int end = min(E, base + EC);
  int cnt = end - base;
  for (int i = base + t; i < end; i += 256) atomicAdd(&lh[dst[i] >> BSH], 1);
  __syncthreads();
  int loc[8];
  int s = 0;
#pragma unroll
  for (int i = 0; i < 8; ++i) {
    loc[i] = lh[t * 8 + i];
    s += loc[i];
  }
  sh[t] = s;
  __syncthreads();
  for (int d = 1; d < 256; d <<= 1) {
    int a = (t >= d) ? sh[t - d] : 0;
    __syncthreads();
    sh[t] += a;
    __syncthreads();
  }
  int run = sh[t] - s;
#pragma unroll
  for (int i = 0; i < 8; ++i) {
    int v = loc[i];
    lh[t * 8 + i] = run;
    run += v;
  }
  __syncthreads();
  for (int i = t; i < NBK; i += 256) lcur[i] = lh[i];
  __syncthreads();
  for (int i = base + t; i < end; i += 256) {
    int d = dst[i];
    int b = d >> BSH;
    int pos = atomicAdd(&lcur[b], 1);
    stage[pos] = ((uint_t)(d & (BNODES - 1)) << 20) | (uint_t)src[i];
  }
  __syncthreads();
  for (int i = t; i < cnt; i += 256) {
    int lo = 0, hi = NBK;
    while (hi - lo > 1) {
      int mid = (lo + hi) >> 1;
      if (lh[mid] <= i) lo = mid; else hi = mid;
    }
    int gb = gmatS[(size_t)lo * B + c];
    parts[gb + (i - lh[lo])] = stage[i];
  }
}

// ---------------- fused: degree + dis + per-bucket CSR (both graphs) ----------
// absRp[b*65 + dl] = absolute start of node (b*64+dl)'s edge list in csrc;
// absRp[b*65 + 64] = segment end. k_agg maps node -> absRp[node + (node>>6)].
// Replaces k_degb + N-wide 3-kernel scan + k_sort2.

__global__ __launch_bounds__(256) void k_degb2(const uint_t* parts0, const uint_t* parts1,
                                               const int* gmatS0, const int* gmatS1,
                                               int* absRp0, int* absRp1,
                                               int* csrc0, int* csrc1,
                                               float* dis0, float* dis1, int B, int n) {
  const uint_t* parts = blockIdx.y ? parts1 : parts0;
  const int* gmatS = blockIdx.y ? gmatS1 : gmatS0;
  int* absRp = blockIdx.y ? absRp1 : absRp0;
  int* csrc = blockIdx.y ? csrc1 : csrc0;
  float* dis = blockIdx.y ? dis1 : dis0;
  __shared__ int cnt[BNODES];
  __shared__ int lcur[BNODES];
  __shared__ int sEx[BNODES + 1];
  int t = threadIdx.x;
  int b = blockIdx.x;
  if (t < BNODES) cnt[t] = 0;
  __syncthreads();
  int s0 = gmatS[(size_t)b * B];
  int s1 = gmatS[(size_t)(b + 1) * B];
  for (int i = s0 + t; i < s1; i += 256) atomicAdd(&cnt[parts[i] >> 20], 1);
  __syncthreads();
  if (t < BNODES) {            // wave 0: 64-wide scan
    int c = cnt[t];
    int incl = c;
#pragma unroll
    for (int d = 1; d < 64; d <<= 1) {
      int y = __shfl_up(incl, d, 64);
      if (t >= d) incl += y;
    }
    sEx[t] = s0 + incl - c;
    lcur[t] = s0 + incl - c;
    if (t == 63) sEx[64] = s0 + incl;
    int node = (b << BSH) + t;
    if (node < n) dis[node] = rsqrtf((float)(c + 1));
  }
  __syncthreads();
  if (t < BNODES + 1) absRp[(size_t)b * 65 + t] = sEx[t];
  for (int i = s0 + t; i < s1; i += 256) {
    uint_t u = parts[i];
    int dl = u >> 20;
    int pos = atomicAdd(&lcur[dl], 1);
    csrc[pos] = (int)((u & 0xFFFFFu) << 8);   // byte offset of the 256B row
  }
}

// ---------------- fp32 -> bf16 convert ----------------

__global__ void k_cvt(const float* __restrict__ x, ushort_t* __restrict__ y, int total4) {
  int i = blockIdx.x * 256 + threadIdx.x;
  if (i < total4) {
    float4 v = *(const float4*)&x[i * 4];
    uint2 p;
    p.x = cvtpk(v.x, v.y);
    p.y = cvtpk(v.z, v.w);
    *(uint2*)&y[i * 4] = p;
  }
}

// ---------------- W pack: all 4 weight matrices in one dispatch ----------------

__global__ void k_packw4(const float* W0, const float* W1, const float* W2,
                         const float* W3, ushort_t* P0, ushort_t* P1,
                         ushort_t* P2, ushort_t* P3) {
  int y = blockIdx.y;
  const float* W = (y == 0) ? W0 : (y == 1) ? W1 : (y == 2) ? W2 : W3;
  ushort_t* P = (y == 0) ? P0 : (y == 1) ? P1 : (y == 2) ? P2 : P3;
  int lim = (y == 3) ? 1024 : 2048;   // enc is K=64 -> KK=2 -> 1024 frags
  int t = blockIdx.x * 256 + threadIdx.x;
  if (t >= lim) return;
  int lane = t & 63;
  int j = (t >> 6) & 7;
  int kk = t >> 9;
  int krow = kk * 32 + (lane >> 4) * 8;
  int col = j * 16 + (lane & 15);
  uint4 v;
  v.x = cvtpk(W[(size_t)(krow + 0) * 128 + col], W[(size_t)(krow + 1) * 128 + col]);
  v.y = cvtpk(W[(size_t)(krow + 2) * 128 + col], W[(size_t)(krow + 3) * 128 + col]);
  v.z = cvtpk(W[(size_t)(krow + 4) * 128 + col], W[(size_t)(krow + 5) * 128 + col]);
  v.w = cvtpk(W[(size_t)(krow + 6) * 128 + col], W[(size_t)(krow + 7) * 128 + col]);
  *(uint4*)&P[(size_t)t * 8] = v;
}

// ---------------- bf16 MFMA GEMM (encoder) ----------------

template <int KK>
__global__ __launch_bounds__(256) void k_gemm_enc(const ushort_t* __restrict__ A,
                                                  const ushort_t* __restrict__ Wp,
                                                  const float* __restrict__ bias,
                                                  ushort_t* __restrict__ C, int n) {
  int lane = threadIdx.x & 63;
  int wid = threadIdx.x >> 6;
  int r0 = (blockIdx.x * 4 + wid) * 16;
  if (r0 >= n) return;
  int arow = r0 + (lane & 15);
  if (arow >= n) arow = n - 1;
  const ushort_t* aptr = A + (size_t)arow * (KK * 32) + (lane >> 4) * 8;

  f32x4 acc[8] = {};
#pragma unroll
  for (int kk = 0; kk < KK; ++kk) {
    short8v a = *(const short8v*)(aptr + kk * 32);
    const ushort_t* wp = Wp + ((size_t)(kk * 8) * 64 + lane) * 8;
#pragma unroll
    for (int j = 0; j < 8; ++j) {
      short8v b = *(const short8v*)(wp + (size_t)j * 512);
      acc[j] = __builtin_amdgcn_mfma_f32_16x16x32_bf16(a, b, acc[j], 0, 0, 0);
    }
  }
  int rbase = r0 + (lane >> 4) * 4;
  int colb = lane & 15;
  float bcol[8];
#pragma unroll
  for (int j = 0; j < 8; ++j) bcol[j] = bias[j * 16 + colb];
#pragma unroll
  for (int reg = 0; reg < 4; ++reg) {
    int row = rbase + reg;
    if (row < n) {
#pragma unroll
      for (int j = 0; j < 8; ++j)
        C[(size_t)row * 128 + j * 16 + colb] = bf16_1(fmaxf(acc[j][reg] + bcol[j], 0.f));
    }
  }
}

// dual-output layer-0 GEMM (one MFMA pass, two dis scalings)
__global__ __launch_bounds__(256) void k_gemm_mfma2(const ushort_t* __restrict__ A,
                                                    const ushort_t* __restrict__ Wp,
                                                    const float* __restrict__ dis1,
                                                    const float* __restrict__ dis2,
                                                    ushort_t* __restrict__ C1,
                                                    ushort_t* __restrict__ C2, int n) {
  int lane = threadIdx.x & 63;
  int wid = threadIdx.x >> 6;
  int r0 = (blockIdx.x * 4 + wid) * 16;
  if (r0 >= n) return;
  int arow = r0 + (lane & 15);
  if (arow >= n) arow = n - 1;
  const ushort_t* aptr = A + (size_t)arow * 128 + (lane >> 4) * 8;

  f32x4 acc[8] = {};
#pragma unroll
  for (int kk = 0; kk < 4; ++kk) {
    short8v a = *(const short8v*)(aptr + kk * 32);
    const ushort_t* wp = Wp + ((size_t)(kk * 8) * 64 + lane) * 8;
#pragma unroll
    for (int j = 0; j < 8; ++j) {
      short8v b = *(const short8v*)(wp + (size_t)j * 512);
      acc[j] = __builtin_amdgcn_mfma_f32_16x16x32_bf16(a, b, acc[j], 0, 0, 0);
    }
  }
  int rbase = r0 + (lane >> 4) * 4;
  int colb = lane & 15;
#pragma unroll
  for (int reg = 0; reg < 4; ++reg) {
    int row = rbase + reg;
    if (row < n) {
      float s1 = dis1[row];
      float s2 = dis2[row];
#pragma unroll
      for (int j = 0; j < 8; ++j) {
        float v = acc[j][reg];
        C1[(size_t)row * 128 + j * 16 + colb] = bf16_1(v * s1);
        C2[(size_t)row * 128 + j * 16 + colb] = bf16_1(v * s2);
      }
    }
  }
}

// dual-branch conv GEMM (layers 1,2): blockIdx.y selects branch
__global__ __launch_bounds__(256) void k_gemm_dual(const ushort_t* A0, const ushort_t* A1,
                                                   const ushort_t* __restrict__ Wp,
                                                   const float* dis0, const float* dis1,
                                                   ushort_t* C0, ushort_t* C1, int n) {
  int br = blockIdx.y;
  const ushort_t* A = br ? A1 : A0;
  const float* dis = br ? dis1 : dis0;
  ushort_t* C = br ? C1 : C0;
  int lane = threadIdx.x & 63;
  int wid = threadIdx.x >> 6;
  int r0 = (blockIdx.x * 4 + wid) * 16;
  if (r0 >= n) return;
  int arow = r0 + (lane & 15);
  if (arow >= n) arow = n - 1;
  const ushort_t* aptr = A + (size_t)arow * 128 + (lane >> 4) * 8;

  f32x4 acc[8] = {};
#pragma unroll
  for (int kk = 0; kk < 4; ++kk) {
    short8v a = *(const short8v*)(aptr + kk * 32);
    const ushort_t* wp = Wp + ((size_t)(kk * 8) * 64 + lane) * 8;
#pragma unroll
    for (int j = 0; j < 8; ++j) {
      short8v b = *(const short8v*)(wp + (size_t)j * 512);
      acc[j] = __builtin_amdgcn_mfma_f32_16x16x32_bf16(a, b, acc[j], 0, 0, 0);
    }
  }
  int rbase = r0 + (lane >> 4) * 4;
  int colb = lane & 15;
#pragma unroll
  for (int reg = 0; reg < 4; ++reg) {
    int row = rbase + reg;
    if (row < n) {
      float s = dis[row];
#pragma unroll
      for (int j = 0; j < 8; ++j)
        C[(size_t)row * 128 + j * 16 + colb] = bf16_1(acc[j][reg] * s);
    }
  }
}

// ---------------- dual-branch aggregation + bias + LayerNorm + ReLU ----------------
// one wave per node; quarter-waves (16 lanes x 16B = full 128-ch row); unroll-4;
// explicit unpack + IEEE f32 adds (bit-identical to round-10 PASS).
// rp is absRp: start = rp[node + (node>>6)].

#define ACC8(U)                                                   \
  a0 += bf_lo(U.x); a1 += bf_hi(U.x); a2 += bf_lo(U.y); a3 += bf_hi(U.y); \
  a4 += bf_lo(U.z); a5 += bf_hi(U.z); a6 += bf_lo(U.w); a7 += bf_hi(U.w);

__global__ __launch_bounds__(256) void k_agg_dual(const char* hwb0, const char* hwb1,
                                                  const int* rpA, const int* rpB,
                                                  const int* csrc0, const int* csrc1,
                                                  const float* dis0, const float* dis1,
                                                  const float* __restrict__ bias,
                                                  const float* __restrict__ g,
                                                  const float* __restrict__ bln,
                                                  uint4* out0, uint4* out1, int n) {
  int br = blockIdx.y;
  const char* hwb = br ? hwb1 : hwb0;
  const int* rp = br ? rpB : rpA;
  const int* csrc = br ? csrc1 : csrc0;
  const float* dis = br ? dis1 : dis0;
  uint4* out4 = br ? out1 : out0;

  int lane = threadIdx.x & 63;
  int q = lane >> 4;
  int cl = lane & 15;
  int clOff = cl << 4;
  int node = blockIdx.x * 4 + (threadIdx.x >> 6);
  if (node >= n) return;
  int ridx = node + (node >> 6);
  int start = rp[ridx], end = rp[ridx + 1];
  float a0 = 0.f, a1 = 0.f, a2 = 0.f, a3 = 0.f, a4 = 0.f, a5 = 0.f, a6 = 0.f, a7 = 0.f;
  int e = start + q;
  for (; e + 12 < end; e += 16) {
    int o0 = csrc[e] + clOff;
    int o1 = csrc[e + 4] + clOff;
    int o2 = csrc[e + 8] + clOff;
    int o3 = csrc[e + 12] + clOff;
    uint4 u = *(const uint4*)(hwb + o0);
    uint4 v = *(const uint4*)(hwb + o1);
    uint4 w = *(const uint4*)(hwb + o2);
    uint4 z = *(const uint4*)(hwb + o3);
    ACC8(u); ACC8(v); ACC8(w); ACC8(z);
  }
  for (; e < end; e += 4) {
    int o0 = csrc[e] + clOff;
    uint4 u = *(const uint4*)(hwb + o0);
    ACC8(u);
  }
  // combine the 4 quarters
#pragma unroll
  for (int m = 16; m < 64; m <<= 1) {
    a0 += __shfl_xor(a0, m, 64); a1 += __shfl_xor(a1, m, 64);
    a2 += __shfl_xor(a2, m, 64); a3 += __shfl_xor(a3, m, 64);
    a4 += __shfl_xor(a4, m, 64); a5 += __shfl_xor(a5, m, 64);
    a6 += __shfl_xor(a6, m, 64); a7 += __shfl_xor(a7, m, 64);
  }
  // self loop (rows pre-scaled by dis[src]); then * dis[node] + bias
  uint4 us = *(const uint4*)(hwb + node * 256 + clOff);
  ACC8(us);
  float dn = dis[node];
  float4 b0 = *(const float4*)&bias[cl * 8];
  float4 b1 = *(const float4*)&bias[cl * 8 + 4];
  a0 = fmaf(a0, dn, b0.x); a1 = fmaf(a1, dn, b0.y);
  a2 = fmaf(a2, dn, b0.z); a3 = fmaf(a3, dn, b0.w);
  a4 = fmaf(a4, dn, b1.x); a5 = fmaf(a5, dn, b1.y);
  a6 = fmaf(a6, dn, b1.z); a7 = fmaf(a7, dn, b1.w);
  // LayerNorm over 128 channels (reduce within 16-lane quarter)
  float s1v = a0 + a1 + a2 + a3 + a4 + a5 + a6 + a7;
  float s2v = a0 * a0 + a1 * a1 + a2 * a2 + a3 * a3 +
              a4 * a4 + a5 * a5 + a6 * a6 + a7 * a7;
#pragma unroll
  for (int m = 1; m < 16; m <<= 1) {
    s1v += __shfl_xor(s1v, m, 64);
    s2v += __shfl_xor(s2v, m, 64);
  }
  float mean = s1v * (1.0f / 128.0f);
  float var = s2v * (1.0f / 128.0f) - mean * mean;
  float rstd = rsqrtf(var + LN_EPS);
  float4 g0 = *(const float4*)&g[cl * 8];
  float4 g1 = *(const float4*)&g[cl * 8 + 4];
  float4 l0 = *(const float4*)&bln[cl * 8];
  float4 l1 = *(const float4*)&bln[cl * 8 + 4];
  float y0 = fmaxf(fmaf((a0 - mean) * rstd, g0.x, l0.x), 0.f);
  float y1 = fmaxf(fmaf((a1 - mean) * rstd, g0.y, l0.y), 0.f);
  float y2 = fmaxf(fmaf((a2 - mean) * rstd, g0.z, l0.z), 0.f);
  float y3 = fmaxf(fmaf((a3 - mean) * rstd, g0.w, l0.w), 0.f);
  float y4 = fmaxf(fmaf((a4 - mean) * rstd, g1.x, l1.x), 0.f);
  float y5 = fmaxf(fmaf((a5 - mean) * rstd, g1.y, l1.y), 0.f);
  float y6 = fmaxf(fmaf((a6 - mean) * rstd, g1.z, l1.z), 0.f);
  float y7 = fmaxf(fmaf((a7 - mean) * rstd, g1.w, l1.w), 0.f);
  if (q == 0) {
    uint4 p;
    p.x = cvtpk(y0, y1);
    p.y = cvtpk(y2, y3);
    p.z = cvtpk(y4, y5);
    p.w = cvtpk(y6, y7);
    out4[(size_t)node * 16 + cl] = p;
  }
}

// ---------------- output head ----------------

__global__ __launch_bounds__(256) void k_out(const ushort_t* __restrict__ x1,
                                             const ushort_t* __restrict__ x2,
                                             const float* __restrict__ w,
                                             const float* __restrict__ b,
                                             float* __restrict__ out, int n) {
  __shared__ float wl[256 * 16];
  __shared__ float bl[16];
  int tid = threadIdx.x;
#pragma unroll
  for (int i = 0; i < 4; ++i) {
    int idx = (i * 256 + tid) * 4;
    *(float4*)&wl[idx] = *(const float4*)&w[idx];
  }
  if (tid < 16) bl[tid] = b[tid];
  __syncthreads();
  int node = blockIdx.x * 256 + tid;
  if (node >= n) return;
  float acc[16];
#pragma unroll
  for (int o = 0; o < 16; ++o) acc[o] = bl[o];

  const ushort_t* xr = x1 + (size_t)node * 128;
#pragma unroll 2
  for (int c = 0; c < 128; c += 8) {
    uint4 xv = *(const uint4*)&xr[c];
    float f0 = bf_lo(xv.x), f1 = bf_hi(xv.x), f2 = bf_lo(xv.y), f3 = bf_hi(xv.y);
    float f4 = bf_lo(xv.z), f5 = bf_hi(xv.z), f6 = bf_lo(xv.w), f7 = bf_hi(xv.w);
#pragma unroll
    for (int o = 0; o < 16; ++o) {
      acc[o] = fmaf(f0, wl[(c + 0) * 16 + o],
               fmaf(f1, wl[(c + 1) * 16 + o],
               fmaf(f2, wl[(c + 2) * 16 + o],
               fmaf(f3, wl[(c + 3) * 16 + o],
               fmaf(f4, wl[(c + 4) * 16 + o],
               fmaf(f5, wl[(c + 5) * 16 + o],
               fmaf(f6, wl[(c + 6) * 16 + o],
               fmaf(f7, wl[(c + 7) * 16 + o], acc[o]))))))));
    }
  }
  const ushort_t* xr2 = x2 + (size_t)node * 128;
#pragma unroll 2
  for (int c = 0; c < 128; c += 8) {
    uint4 xv = *(const uint4*)&xr2[c];
    float f0 = bf_lo(xv.x), f1 = bf_hi(xv.x), f2 = bf_lo(xv.y), f3 = bf_hi(xv.y);
    float f4 = bf_lo(xv.z), f5 = bf_hi(xv.z), f6 = bf_lo(xv.w), f7 = bf_hi(xv.w);
#pragma unroll
    for (int o = 0; o < 16; ++o) {
      acc[o] = fmaf(f0, wl[(128 + c + 0) * 16 + o],
               fmaf(f1, wl[(128 + c + 1) * 16 + o],
               fmaf(f2, wl[(128 + c + 2) * 16 + o],
               fmaf(f3, wl[(128 + c + 3) * 16 + o],
               fmaf(f4, wl[(128 + c + 4) * 16 + o],
               fmaf(f5, wl[(128 + c + 5) * 16 + o],
               fmaf(f6, wl[(128 + c + 6) * 16 + o],
               fmaf(f7, wl[(128 + c + 7) * 16 + o], acc[o]))))))));
    }
  }
#pragma unroll
  for (int o = 0; o < 4; ++o) {
    *(float4*)&out[(size_t)node * 16 + o * 4] =
        make_float4(acc[o * 4], acc[o * 4 + 1], acc[o * 4 + 2], acc[o * 4 + 3]);
  }
}

// ---------------- host ----------------

extern "C" void kernel_launch(void* const* d_in, const int* in_sizes, int n_in,
                              void* d_out, int out_size, void* d_ws, size_t ws_size,
                              hipStream_t stream) {
  const float* x = (const float*)d_in[0];
  const int* ei1 = (const int*)d_in[1];
  const int* ei2 = (const int*)d_in[2];
  const float* enc_w = (const float*)d_in[3];
  const float* enc_b = (const float*)d_in[4];
  const float* conv_w[3] = {(const float*)d_in[5], (const float*)d_in[9], (const float*)d_in[13]};
  const float* conv_b[3] = {(const float*)d_in[6], (const float*)d_in[10], (const float*)d_in[14]};
  const float* ln_g[3] = {(const float*)d_in[7], (const float*)d_in[11], (const float*)d_in[15]};
  const float* ln_b[3] = {(const float*)d_in[8], (const float*)d_in[12], (const float*)d_in[16]};
  const float* out_w = (const float*)d_in[17];
  const float* out_b = (const float*)d_in[18];
  float* out = (float*)d_out;

  const int N = NN;
  const int E = in_sizes[1] / 2;
  const int B = (E + EC - 1) / EC;       // partition chunks
  const int M = NBK * B;                 // histogram matrix size

  char* ws = (char*)d_ws;
  size_t off = 0;
  auto alloc = [&](size_t bytes) -> char* {
    char* p = ws + off;
    off += (bytes + 255) & ~(size_t)255;
    return p;
  };
  ushort_t* h0 = (ushort_t*)alloc((size_t)N * 128 * 2);
  ushort_t* hb = (ushort_t*)alloc((size_t)N * 128 * 2);
  ushort_t* hb2 = (ushort_t*)alloc((size_t)N * 128 * 2);
  ushort_t* p1 = (ushort_t*)alloc((size_t)N * 128 * 2);
  ushort_t* p2 = (ushort_t*)alloc((size_t)N * 128 * 2);
  ushort_t* xb = (ushort_t*)alloc((size_t)N * 64 * 2);
  ushort_t* wpk[3];
  for (int l = 0; l < 3; ++l) wpk[l] = (ushort_t*)alloc(2048 * 8 * 2);
  ushort_t* wpe = (ushort_t*)alloc(1024 * 8 * 2);

  struct G {
    float* dis; int* absRp; int* gmatC; int* gmatS; int* bsum;
    uint_t* parts; int* csrc; const int* src; const int* dst;
  } g[2];
  for (int i = 0; i < 2; ++i) {
    g[i].dis = (float*)alloc((size_t)N * 4);
    g[i].absRp = (int*)alloc((size_t)NBK * 65 * 4);
    g[i].gmatC = (int*)alloc((size_t)M * 4);
    g[i].gmatS = (int*)alloc((size_t)(M + 1) * 4);
    g[i].bsum = (int*)alloc(64 * 4);
    g[i].parts = (uint_t*)alloc((size_t)E * 4);
    g[i].csrc = (int*)alloc((size_t)E * 4);
  }
  g[0].src = ei1; g[0].dst = ei1 + E;
  g[1].src = ei2; g[1].dst = ei2 + E;

  int nScanM = (M + 8191) / 8192;

  // CSR build — both graphs per dispatch (gridDim.y = 2)
  k_phist<<<dim3(B, 2), 256, 0, stream>>>(g[0].dst, g[1].dst, g[0].gmatC, g[1].gmatC, E, B);
  k_scanA32<<<dim3(nScanM, 2), 256, 0, stream>>>(g[0].gmatC, g[1].gmatC,
                                                 g[0].gmatS, g[1].gmatS,
                                                 g[0].bsum, g[1].bsum, M);
  k_scanB<<<dim3(1, 2), 64, 0, stream>>>(g[0].bsum, g[1].bsum, nScanM);
  k_scanC32<<<dim3((M + 1 + 255) / 256, 2), 256, 0, stream>>>(g[0].gmatS, g[1].gmatS,
                                                              g[0].bsum, g[1].bsum, M, E);
  k_pscatter<<<dim3(B, 2), 256, 0, stream>>>(g[0].src, g[1].src, g[0].dst, g[1].dst,
                                             g[0].gmatS, g[1].gmatS,
                                             g[0].parts, g[1].parts, E, B);
  k_degb2<<<dim3(NBK, 2), 256, 0, stream>>>(g[0].parts, g[1].parts,
                                            g[0].gmatS, g[1].gmatS,
                                            g[0].absRp, g[1].absRp,
                                            g[0].csrc, g[1].csrc,
                                            g[0].dis, g[1].dis, B, N);

  // weights + input conversion
  k_packw4<<<dim3(8, 4), 256, 0, stream>>>(conv_w[0], conv_w[1], conv_w[2], enc_w,
                                           wpk[0], wpk[1], wpk[2], wpe);
  k_cvt<<<(N * 64 / 4 + 255) / 256, 256, 0, stream>>>(x, xb, N * 64 / 4);

  int gb = (N + 63) / 64;
  int ga = (N + 3) / 4;
  // shared encoder -> h0
  k_gemm_enc<2><<<gb, 256, 0, stream>>>(xb, wpe, enc_b, h0, N);

  // layer 0: shared GEMM (dual output), dual-branch agg
  k_gemm_mfma2<<<gb, 256, 0, stream>>>(h0, wpk[0], g[0].dis, g[1].dis, hb, hb2, N);
  k_agg_dual<<<dim3(ga, 2), 256, 0, stream>>>((const char*)hb, (const char*)hb2,
                                              g[0].absRp, g[1].absRp,
                                              g[0].csrc, g[1].csrc,
                                              g[0].dis, g[1].dis,
                                              conv_b[0], ln_g[0], ln_b[0],
                                              (uint4*)p1, (uint4*)p2, N);
  // layers 1,2: dual-branch GEMM + dual-branch agg
  for (int l = 1; l < 3; ++l) {
    k_gemm_dual<<<dim3(gb, 2), 256, 0, stream>>>(p1, p2, wpk[l], g[0].dis, g[1].dis,
                                                 hb, hb2, N);
    k_agg_dual<<<dim3(ga, 2), 256, 0, stream>>>((const char*)hb, (const char*)hb2,
                                                g[0].absRp, g[1].absRp,
                                                g[0].csrc, g[1].csrc,
                                                g[0].dis, g[1].dis,
                                                conv_b[l], ln_g[l], ln_b[l],
                                                (uint4*)p1, (uint4*)p2, N);
  }

  k_out<<<(N + 255) / 256, 256, 0, stream>>>(p1, p2, out_w, out_b, out, N);
}

// Round 13
// 608.519 us; speedup vs baseline: 12.8786x; 1.0294x over previous
//
#include <hip/hip_runtime.h>

#define NN 100000
#define LN_EPS 1e-5f
#define BSH 6                       // 64 nodes per bucket
#define BNODES 64
#define NBK ((NN + 63) >> 6)        // 1563 buckets
#define EC 6144                     // edges per partition chunk

typedef unsigned int uint_t;
typedef unsigned short ushort_t;
typedef __attribute__((ext_vector_type(8))) short short8v;
typedef __attribute__((ext_vector_type(4))) float f32x4;

// ---- bf16 helpers ----
// Manual RNE pack ONLY (HW cvt_pk rounds differently: r8; dot2 truncates: r9).
// k_agg loop SHAPE is load-bearing (r12: merging the tail into the unrolled body
// changed FP association and broke absmax) — do not restructure the agg loops.

__device__ __forceinline__ uint_t cvtpk(float a, float b) {
  uint_t ua = __float_as_uint(a);
  ua = (ua + 0x7FFFu + ((ua >> 16) & 1u)) >> 16;
  uint_t ub = __float_as_uint(b);
  ub = (ub + 0x7FFFu + ((ub >> 16) & 1u)) & 0xFFFF0000u;
  return ua | ub;
}
__device__ __forceinline__ ushort_t bf16_1(float x) {
  uint_t u = __float_as_uint(x);
  return (ushort_t)((u + 0x7FFFu + ((u >> 16) & 1u)) >> 16);
}
__device__ __forceinline__ float bf_lo(uint_t u) { return __uint_as_float(u << 16); }
__device__ __forceinline__ float bf_hi(uint_t u) { return __uint_as_float(u & 0xFFFF0000u); }

// ---------------- scan over gmat matrices (both graphs via blockIdx.y) ------

__global__ __launch_bounds__(256) void k_scanA32(const int* in0, const int* in1,
                                                 int* out0, int* out1,
                                                 int* bsum0, int* bsum1, int n) {
  const int* in = blockIdx.y ? in1 : in0;
  int* out = blockIdx.y ? out1 : out0;
  int* bsum = blockIdx.y ? bsum1 : bsum0;
  __shared__ int sh[256];
  int t = threadIdx.x;
  int base = blockIdx.x * 8192 + t * 32;
  int v[32];
  int s = 0;
#pragma unroll
  for (int i = 0; i < 32; ++i) {
    int idx = base + i;
    v[i] = (idx < n) ? in[idx] : 0;
    s += v[i];
  }
  sh[t] = s;
  __syncthreads();
  for (int d = 1; d < 256; d <<= 1) {
    int a = (t >= d) ? sh[t - d] : 0;
    __syncthreads();
    sh[t] += a;
    __syncthreads();
  }
  int run = sh[t] - s;
  if (t == 255) bsum[blockIdx.x] = sh[255];
#pragma unroll
  for (int i = 0; i < 32; ++i) {
    int idx = base + i;
    if (idx < n) out[idx] = run;
    run += v[i];
  }
}

__global__ void k_scanB(int* bsum0, int* bsum1, int nb) {
  int* bsum = blockIdx.y ? bsum1 : bsum0;
  int t = threadIdx.x;
  int x = (t < nb) ? bsum[t] : 0;
  int incl = x;
#pragma unroll
  for (int d = 1; d < 64; d <<= 1) {
    int y = __shfl_up(incl, d, 64);
    if (t >= d) incl += y;
  }
  if (t < nb) bsum[t] = incl - x;
}

__global__ void k_scanC32(int* rp0, int* rp1, const int* bsum0, const int* bsum1,
                          int n, int total) {
  int* rp = blockIdx.y ? rp1 : rp0;
  const int* bsum = blockIdx.y ? bsum1 : bsum0;
  int i = blockIdx.x * 256 + threadIdx.x;
  if (i < n) rp[i] += bsum[i >> 13];
  else if (i == n) rp[n] = total;
}

// ---------------- partition: per-chunk histogram over buckets (both graphs) --

__global__ __launch_bounds__(256) void k_phist(const int* dst0, const int* dst1,
                                               int* gmatC0, int* gmatC1, int E, int B) {
  const int* dst = blockIdx.y ? dst1 : dst0;
  int* gmatC = blockIdx.y ? gmatC1 : gmatC0;
  __shared__ int lh[NBK];
  int t = threadIdx.x;
  for (int i = t; i < NBK; i += 256) lh[i] = 0;
  __syncthreads();
  int base = blockIdx.x * EC;
  int end = min(E, base + EC);
  for (int i = base + t; i < end; i += 256) atomicAdd(&lh[dst[i] >> BSH], 1);
  __syncthreads();
  for (int b = t; b < NBK; b += 256) gmatC[(size_t)b * B + blockIdx.x] = lh[b];
}

// LDS counting sort of one chunk; flat copy-out via binary search (both graphs).
// parts[pos] = (dst&63)<<20 | src
__global__ __launch_bounds__(256) void k_pscatter(const int* src0, const int* src1,
                                                  const int* dst0, const int* dst1,
                                                  const int* gmatS0, const int* gmatS1,
                                                  uint_t* parts0, uint_t* parts1,
                                                  int E, int B) {
  const int* src = blockIdx.y ? src1 : src0;
  const int* dst = blockIdx.y ? dst1 : dst0;
  const int* gmatS = blockIdx.y ? gmatS1 : gmatS0;
  uint_t* parts = blockIdx.y ? parts1 : parts0;
  __shared__ uint_t stage[EC];   // 24 KB
  __shared__ int lh[2048];
  __shared__ int lcur[NBK];
  __shared__ int sh[256];
  int t = threadIdx.x;
  int c = blockIdx.x;
  for (int i = t; i < 2048; i += 256) lh[i] = 0;
  __syncthreads();
  int base = c * EC;
  int end = min(E, base + EC);
  int cnt = end - base;
  for (int i = base + t; i < end; i += 256) atomicAdd(&lh[dst[i] >> BSH], 1);
  __syncthreads();
  int loc[8];
  int s = 0;
#pragma unroll
  for (int i = 0; i < 8; ++i) {
    loc[i] = lh[t * 8 + i];
    s += loc[i];
  }
  sh[t] = s;
  __syncthreads();
  for (int d = 1; d < 256; d <<= 1) {
    int a = (t >= d) ? sh[t - d] : 0;
    __syncthreads();
    sh[t] += a;
    __syncthreads();
  }
  int run = sh[t] - s;
#pragma unroll
  for (int i = 0; i < 8; ++i) {
    int v = loc[i];
    lh[t * 8 + i] = run;
    run += v;
  }
  __syncthreads();
  for (int i = t; i < NBK; i += 256) lcur[i] = lh[i];
  __syncthreads();
  for (int i = base + t; i < end; i += 256) {
    int d = dst[i];
    int b = d >> BSH;
    int pos = atomicAdd(&lcur[b], 1);
    stage[pos] = ((uint_t)(d & (BNODES - 1)) << 20) | (uint_t)src[i];
  }
  __syncthreads();
  for (int i = t; i < cnt; i += 256) {
    int lo = 0, hi = NBK;
    while (hi - lo > 1) {
      int mid = (lo + hi) >> 1;
      if (lh[mid] <= i) lo = mid; else hi = mid;
    }
    int gb = gmatS[(size_t)lo * B + c];
    parts[gb + (i - lh[lo])] = stage[i];
  }
}

// ---------------- fused: degree + dis + per-bucket CSR (both graphs) ----------
// absRp[b*65 + dl] = absolute start of node (b*64+dl)'s edge list in csrc;
// absRp[b*65 + 64] = segment end. k_agg maps node -> absRp[node + (node>>6)].

__global__ __launch_bounds__(256) void k_degb2(const uint_t* parts0, const uint_t* parts1,
                                               const int* gmatS0, const int* gmatS1,
                                               int* absRp0, int* absRp1,
                                               int* csrc0, int* csrc1,
                                               float* dis0, float* dis1, int B, int n) {
  const uint_t* parts = blockIdx.y ? parts1 : parts0;
  const int* gmatS = blockIdx.y ? gmatS1 : gmatS0;
  int* absRp = blockIdx.y ? absRp1 : absRp0;
  int* csrc = blockIdx.y ? csrc1 : csrc0;
  float* dis = blockIdx.y ? dis1 : dis0;
  __shared__ int cnt[BNODES];
  __shared__ int lcur[BNODES];
  __shared__ int sEx[BNODES + 1];
  int t = threadIdx.x;
  int b = blockIdx.x;
  if (t < BNODES) cnt[t] = 0;
  __syncthreads();
  int s0 = gmatS[(size_t)b * B];
  int s1 = gmatS[(size_t)(b + 1) * B];
  for (int i = s0 + t; i < s1; i += 256) atomicAdd(&cnt[parts[i] >> 20], 1);
  __syncthreads();
  if (t < BNODES) {            // wave 0: 64-wide scan
    int c = cnt[t];
    int incl = c;
#pragma unroll
    for (int d = 1; d < 64; d <<= 1) {
      int y = __shfl_up(incl, d, 64);
      if (t >= d) incl += y;
    }
    sEx[t] = s0 + incl - c;
    lcur[t] = s0 + incl - c;
    if (t == 63) sEx[64] = s0 + incl;
    int node = (b << BSH) + t;
    if (node < n) dis[node] = rsqrtf((float)(c + 1));
  }
  __syncthreads();
  if (t < BNODES + 1) absRp[(size_t)b * 65 + t] = sEx[t];
  for (int i = s0 + t; i < s1; i += 256) {
    uint_t u = parts[i];
    int dl = u >> 20;
    int pos = atomicAdd(&lcur[dl], 1);
    csrc[pos] = (int)((u & 0xFFFFFu) << 8);   // byte offset of the 256B row
  }
}

// ---------------- fused prep: pack 4 weight matrices + fp32->bf16 x ----------

__global__ void k_prep(const float* W0, const float* W1, const float* W2,
                       const float* W3, ushort_t* P0, ushort_t* P1,
                       ushort_t* P2, ushort_t* P3,
                       const float* __restrict__ x, ushort_t* __restrict__ xb,
                       int total4) {
  int y = blockIdx.y;
  if (y < 4) {
    const float* W = (y == 0) ? W0 : (y == 1) ? W1 : (y == 2) ? W2 : W3;
    ushort_t* P = (y == 0) ? P0 : (y == 1) ? P1 : (y == 2) ? P2 : P3;
    int lim = (y == 3) ? 1024 : 2048;   // enc is K=64 -> KK=2 -> 1024 frags
    int t = blockIdx.x * 256 + threadIdx.x;
    if (t >= lim) return;
    int lane = t & 63;
    int j = (t >> 6) & 7;
    int kk = t >> 9;
    int krow = kk * 32 + (lane >> 4) * 8;
    int col = j * 16 + (lane & 15);
    uint4 v;
    v.x = cvtpk(W[(size_t)(krow + 0) * 128 + col], W[(size_t)(krow + 1) * 128 + col]);
    v.y = cvtpk(W[(size_t)(krow + 2) * 128 + col], W[(size_t)(krow + 3) * 128 + col]);
    v.z = cvtpk(W[(size_t)(krow + 4) * 128 + col], W[(size_t)(krow + 5) * 128 + col]);
    v.w = cvtpk(W[(size_t)(krow + 6) * 128 + col], W[(size_t)(krow + 7) * 128 + col]);
    *(uint4*)&P[(size_t)t * 8] = v;
  } else {
    int i = blockIdx.x * 256 + threadIdx.x;
    if (i < total4) {
      float4 v = *(const float4*)&x[i * 4];
      uint2 p;
      p.x = cvtpk(v.x, v.y);
      p.y = cvtpk(v.z, v.w);
      *(uint2*)&xb[i * 4] = p;
    }
  }
}

// ---------------- bf16 MFMA GEMM (encoder) ----------------

template <int KK>
__global__ __launch_bounds__(256) void k_gemm_enc(const ushort_t* __restrict__ A,
                                                  const ushort_t* __restrict__ Wp,
                                                  const float* __restrict__ bias,
                                                  ushort_t* __restrict__ C, int n) {
  int lane = threadIdx.x & 63;
  int wid = threadIdx.x >> 6;
  int r0 = (blockIdx.x * 4 + wid) * 16;
  if (r0 >= n) return;
  int arow = r0 + (lane & 15);
  if (arow >= n) arow = n - 1;
  const ushort_t* aptr = A + (size_t)arow * (KK * 32) + (lane >> 4) * 8;

  f32x4 acc[8] = {};
#pragma unroll
  for (int kk = 0; kk < KK; ++kk) {
    short8v a = *(const short8v*)(aptr + kk * 32);
    const ushort_t* wp = Wp + ((size_t)(kk * 8) * 64 + lane) * 8;
#pragma unroll
    for (int j = 0; j < 8; ++j) {
      short8v b = *(const short8v*)(wp + (size_t)j * 512);
      acc[j] = __builtin_amdgcn_mfma_f32_16x16x32_bf16(a, b, acc[j], 0, 0, 0);
    }
  }
  int rbase = r0 + (lane >> 4) * 4;
  int colb = lane & 15;
  float bcol[8];
#pragma unroll
  for (int j = 0; j < 8; ++j) bcol[j] = bias[j * 16 + colb];
#pragma unroll
  for (int reg = 0; reg < 4; ++reg) {
    int row = rbase + reg;
    if (row < n) {
#pragma unroll
      for (int j = 0; j < 8; ++j)
        C[(size_t)row * 128 + j * 16 + colb] = bf16_1(fmaxf(acc[j][reg] + bcol[j], 0.f));
    }
  }
}

// dual-output layer-0 GEMM (one MFMA pass, two dis scalings)
__global__ __launch_bounds__(256) void k_gemm_mfma2(const ushort_t* __restrict__ A,
                                                    const ushort_t* __restrict__ Wp,
                                                    const float* __restrict__ dis1,
                                                    const float* __restrict__ dis2,
                                                    ushort_t* __restrict__ C1,
                                                    ushort_t* __restrict__ C2, int n) {
  int lane = threadIdx.x & 63;
  int wid = threadIdx.x >> 6;
  int r0 = (blockIdx.x * 4 + wid) * 16;
  if (r0 >= n) return;
  int arow = r0 + (lane & 15);
  if (arow >= n) arow = n - 1;
  const ushort_t* aptr = A + (size_t)arow * 128 + (lane >> 4) * 8;

  f32x4 acc[8] = {};
#pragma unroll
  for (int kk = 0; kk < 4; ++kk) {
    short8v a = *(const short8v*)(aptr + kk * 32);
    const ushort_t* wp = Wp + ((size_t)(kk * 8) * 64 + lane) * 8;
#pragma unroll
    for (int j = 0; j < 8; ++j) {
      short8v b = *(const short8v*)(wp + (size_t)j * 512);
      acc[j] = __builtin_amdgcn_mfma_f32_16x16x32_bf16(a, b, acc[j], 0, 0, 0);
    }
  }
  int rbase = r0 + (lane >> 4) * 4;
  int colb = lane & 15;
#pragma unroll
  for (int reg = 0; reg < 4; ++reg) {
    int row = rbase + reg;
    if (row < n) {
      float s1 = dis1[row];
      float s2 = dis2[row];
#pragma unroll
      for (int j = 0; j < 8; ++j) {
        float v = acc[j][reg];
        C1[(size_t)row * 128 + j * 16 + colb] = bf16_1(v * s1);
        C2[(size_t)row * 128 + j * 16 + colb] = bf16_1(v * s2);
      }
    }
  }
}

// dual-branch conv GEMM (layers 1,2): blockIdx.y selects branch
__global__ __launch_bounds__(256) void k_gemm_dual(const ushort_t* A0, const ushort_t* A1,
                                                   const ushort_t* __restrict__ Wp,
                                                   const float* dis0, const float* dis1,
                                                   ushort_t* C0, ushort_t* C1, int n) {
  int br = blockIdx.y;
  const ushort_t* A = br ? A1 : A0;
  const float* dis = br ? dis1 : dis0;
  ushort_t* C = br ? C1 : C0;
  int lane = threadIdx.x & 63;
  int wid = threadIdx.x >> 6;
  int r0 = (blockIdx.x * 4 + wid) * 16;
  if (r0 >= n) return;
  int arow = r0 + (lane & 15);
  if (arow >= n) arow = n - 1;
  const ushort_t* aptr = A + (size_t)arow * 128 + (lane >> 4) * 8;

  f32x4 acc[8] = {};
#pragma unroll
  for (int kk = 0; kk < 4; ++kk) {
    short8v a = *(const short8v*)(aptr + kk * 32);
    const ushort_t* wp = Wp + ((size_t)(kk * 8) * 64 + lane) * 8;
#pragma unroll
    for (int j = 0; j < 8; ++j) {
      short8v b = *(const short8v*)(wp + (size_t)j * 512);
      acc[j] = __builtin_amdgcn_mfma_f32_16x16x32_bf16(a, b, acc[j], 0, 0, 0);
    }
  }
  int rbase = r0 + (lane >> 4) * 4;
  int colb = lane & 15;
#pragma unroll
  for (int reg = 0; reg < 4; ++reg) {
    int row = rbase + reg;
    if (row < n) {
      float s = dis[row];
#pragma unroll
      for (int j = 0; j < 8; ++j)
        C[(size_t)row * 128 + j * 16 + colb] = bf16_1(acc[j][reg] * s);
    }
  }
}

// ---------------- dual-branch aggregation + bias + LayerNorm + ReLU ----------------
// one wave per node; quarter-waves (16 lanes x 16B = full 128-ch row); unroll-4.
// Round-11 loop SHAPE preserved exactly (load-bearing for FP association — r12).
// Only change: edge indices staged into per-wave LDS via ONE coalesced 64-wide
// load, so the gather address chain reads LDS (~60cy) instead of global (~200-900cy).

#define ACC8(U)                                                   \
  a0 += bf_lo(U.x); a1 += bf_hi(U.x); a2 += bf_lo(U.y); a3 += bf_hi(U.y); \
  a4 += bf_lo(U.z); a5 += bf_hi(U.z); a6 += bf_lo(U.w); a7 += bf_hi(U.w);

__global__ __launch_bounds__(256) void k_agg_dual(const char* hwb0, const char* hwb1,
                                                  const int* rpA, const int* rpB,
                                                  const int* csrc0, const int* csrc1,
                                                  const float* dis0, const float* dis1,
                                                  const float* __restrict__ bias,
                                                  const float* __restrict__ g,
                                                  const float* __restrict__ bln,
                                                  uint4* out0, uint4* out1, int n) {
  int br = blockIdx.y;
  const char* hwb = br ? hwb1 : hwb0;
  const int* rp = br ? rpB : rpA;
  const int* csrc = br ? csrc1 : csrc0;
  const float* dis = br ? dis1 : dis0;
  uint4* out4 = br ? out1 : out0;

  __shared__ int sidx[4][64];   // per-wave index staging (no cross-wave sharing)
  int lane = threadIdx.x & 63;
  int wv = threadIdx.x >> 6;
  int q = lane >> 4;
  int cl = lane & 15;
  int clOff = cl << 4;
  int node = blockIdx.x * 4 + wv;
  if (node >= n) return;
  int ridx = node + (node >> 6);
  int start = rp[ridx];
  int endAbs = rp[ridx + 1];
  float a0 = 0.f, a1 = 0.f, a2 = 0.f, a3 = 0.f, a4 = 0.f, a5 = 0.f, a6 = 0.f, a7 = 0.f;

  int base = start;
  while (base < endAbs) {
    int take = min(endAbs - base, 64);
    if (lane < take) sidx[wv][lane] = csrc[base + lane];   // one coalesced load
    int e = q;
    for (; e + 12 < take; e += 16) {
      int o0 = sidx[wv][e] + clOff;
      int o1 = sidx[wv][e + 4] + clOff;
      int o2 = sidx[wv][e + 8] + clOff;
      int o3 = sidx[wv][e + 12] + clOff;
      uint4 u = *(const uint4*)(hwb + o0);
      uint4 v = *(const uint4*)(hwb + o1);
      uint4 w = *(const uint4*)(hwb + o2);
      uint4 z = *(const uint4*)(hwb + o3);
      ACC8(u); ACC8(v); ACC8(w); ACC8(z);
    }
    for (; e < take; e += 4) {
      int o0 = sidx[wv][e] + clOff;
      uint4 u = *(const uint4*)(hwb + o0);
      ACC8(u);
    }
    base += take;
  }
  // combine the 4 quarters
#pragma unroll
  for (int m = 16; m < 64; m <<= 1) {
    a0 += __shfl_xor(a0, m, 64); a1 += __shfl_xor(a1, m, 64);
    a2 += __shfl_xor(a2, m, 64); a3 += __shfl_xor(a3, m, 64);
    a4 += __shfl_xor(a4, m, 64); a5 += __shfl_xor(a5, m, 64);
    a6 += __shfl_xor(a6, m, 64); a7 += __shfl_xor(a7, m, 64);
  }
  // self loop (rows pre-scaled by dis[src]); then * dis[node] + bias
  uint4 us = *(const uint4*)(hwb + node * 256 + clOff);
  ACC8(us);
  float dn = dis[node];
  float4 b0 = *(const float4*)&bias[cl * 8];
  float4 b1 = *(const float4*)&bias[cl * 8 + 4];
  a0 = fmaf(a0, dn, b0.x); a1 = fmaf(a1, dn, b0.y);
  a2 = fmaf(a2, dn, b0.z); a3 = fmaf(a3, dn, b0.w);
  a4 = fmaf(a4, dn, b1.x); a5 = fmaf(a5, dn, b1.y);
  a6 = fmaf(a6, dn, b1.z); a7 = fmaf(a7, dn, b1.w);
  // LayerNorm over 128 channels (reduce within 16-lane quarter)
  float s1v = a0 + a1 + a2 + a3 + a4 + a5 + a6 + a7;
  float s2v = a0 * a0 + a1 * a1 + a2 * a2 + a3 * a3 +
              a4 * a4 + a5 * a5 + a6 * a6 + a7 * a7;
#pragma unroll
  for (int m = 1; m < 16; m <<= 1) {
    s1v += __shfl_xor(s1v, m, 64);
    s2v += __shfl_xor(s2v, m, 64);
  }
  float mean = s1v * (1.0f / 128.0f);
  float var = s2v * (1.0f / 128.0f) - mean * mean;
  float rstd = rsqrtf(var + LN_EPS);
  float4 g0 = *(const float4*)&g[cl * 8];
  float4 g1 = *(const float4*)&g[cl * 8 + 4];
  float4 l0 = *(const float4*)&bln[cl * 8];
  float4 l1 = *(const float4*)&bln[cl * 8 + 4];
  float y0 = fmaxf(fmaf((a0 - mean) * rstd, g0.x, l0.x), 0.f);
  float y1 = fmaxf(fmaf((a1 - mean) * rstd, g0.y, l0.y), 0.f);
  float y2 = fmaxf(fmaf((a2 - mean) * rstd, g0.z, l0.z), 0.f);
  float y3 = fmaxf(fmaf((a3 - mean) * rstd, g0.w, l0.w), 0.f);
  float y4 = fmaxf(fmaf((a4 - mean) * rstd, g1.x, l1.x), 0.f);
  float y5 = fmaxf(fmaf((a5 - mean) * rstd, g1.y, l1.y), 0.f);
  float y6 = fmaxf(fmaf((a6 - mean) * rstd, g1.z, l1.z), 0.f);
  float y7 = fmaxf(fmaf((a7 - mean) * rstd, g1.w, l1.w), 0.f);
  if (q == 0) {
    uint4 p;
    p.x = cvtpk(y0, y1);
    p.y = cvtpk(y2, y3);
    p.z = cvtpk(y4, y5);
    p.w = cvtpk(y6, y7);
    out4[(size_t)node * 16 + cl] = p;
  }
}

// ---------------- output head ----------------

__global__ __launch_bounds__(256) void k_out(const ushort_t* __restrict__ x1,
                                             const ushort_t* __restrict__ x2,
                                             const float* __restrict__ w,
                                             const float* __restrict__ b,
                                             float* __restrict__ out, int n) {
  __shared__ float wl[256 * 16];
  __shared__ float bl[16];
  int tid = threadIdx.x;
#pragma unroll
  for (int i = 0; i < 4; ++i) {
    int idx = (i * 256 + tid) * 4;
    *(float4*)&wl[idx] = *(const float4*)&w[idx];
  }
  if (tid < 16) bl[tid] = b[tid];
  __syncthreads();
  int node = blockIdx.x * 256 + tid;
  if (node >= n) return;
  float acc[16];
#pragma unroll
  for (int o = 0; o < 16; ++o) acc[o] = bl[o];

  const ushort_t* xr = x1 + (size_t)node * 128;
#pragma unroll 2
  for (int c = 0; c < 128; c += 8) {
    uint4 xv = *(const uint4*)&xr[c];
    float f0 = bf_lo(xv.x), f1 = bf_hi(xv.x), f2 = bf_lo(xv.y), f3 = bf_hi(xv.y);
    float f4 = bf_lo(xv.z), f5 = bf_hi(xv.z), f6 = bf_lo(xv.w), f7 = bf_hi(xv.w);
#pragma unroll
    for (int o = 0; o < 16; ++o) {
      acc[o] = fmaf(f0, wl[(c + 0) * 16 + o],
               fmaf(f1, wl[(c + 1) * 16 + o],
               fmaf(f2, wl[(c + 2) * 16 + o],
               fmaf(f3, wl[(c + 3) * 16 + o],
               fmaf(f4, wl[(c + 4) * 16 + o],
               fmaf(f5, wl[(c + 5) * 16 + o],
               fmaf(f6, wl[(c + 6) * 16 + o],
               fmaf(f7, wl[(c + 7) * 16 + o], acc[o]))))))));
    }
  }
  const ushort_t* xr2 = x2 + (size_t)node * 128;
#pragma unroll 2
  for (int c = 0; c < 128; c += 8) {
    uint4 xv = *(const uint4*)&xr2[c];
    float f0 = bf_lo(xv.x), f1 = bf_hi(xv.x), f2 = bf_lo(xv.y), f3 = bf_hi(xv.y);
    float f4 = bf_lo(xv.z), f5 = bf_hi(xv.z), f6 = bf_lo(xv.w), f7 = bf_hi(xv.w);
#pragma unroll
    for (int o = 0; o < 16; ++o) {
      acc[o] = fmaf(f0, wl[(128 + c + 0) * 16 + o],
               fmaf(f1, wl[(128 + c + 1) * 16 + o],
               fmaf(f2, wl[(128 + c + 2) * 16 + o],
               fmaf(f3, wl[(128 + c + 3) * 16 + o],
               fmaf(f4, wl[(128 + c + 4) * 16 + o],
               fmaf(f5, wl[(128 + c + 5) * 16 + o],
               fmaf(f6, wl[(128 + c + 6) * 16 + o],
               fmaf(f7, wl[(128 + c + 7) * 16 + o], acc[o]))))))));
    }
  }
#pragma unroll
  for (int o = 0; o < 4; ++o) {
    *(float4*)&out[(size_t)node * 16 + o * 4] =
        make_float4(acc[o * 4], acc[o * 4 + 1], acc[o * 4 + 2], acc[o * 4 + 3]);
  }
}

// ---------------- host ----------------

extern "C" void kernel_launch(void* const* d_in, const int* in_sizes, int n_in,
                              void* d_out, int out_size, void* d_ws, size_t ws_size,
                              hipStream_t stream) {
  const float* x = (const float*)d_in[0];
  const int* ei1 = (const int*)d_in[1];
  const int* ei2 = (const int*)d_in[2];
  const float* enc_w = (const float*)d_in[3];
  const float* enc_b = (const float*)d_in[4];
  const float* conv_w[3] = {(const float*)d_in[5], (const float*)d_in[9], (const float*)d_in[13]};
  const float* conv_b[3] = {(const float*)d_in[6], (const float*)d_in[10], (const float*)d_in[14]};
  const float* ln_g[3] = {(const float*)d_in[7], (const float*)d_in[11], (const float*)d_in[15]};
  const float* ln_b[3] = {(const float*)d_in[8], (const float*)d_in[12], (const float*)d_in[16]};
  const float* out_w = (const float*)d_in[17];
  const float* out_b = (const float*)d_in[18];
  float* out = (float*)d_out;

  const int N = NN;
  const int E = in_sizes[1] / 2;
  const int B = (E + EC - 1) / EC;       // partition chunks
  const int M = NBK * B;                 // histogram matrix size

  char* ws = (char*)d_ws;
  size_t off = 0;
  auto alloc = [&](size_t bytes) -> char* {
    char* p = ws + off;
    off += (bytes + 255) & ~(size_t)255;
    return p;
  };
  ushort_t* h0 = (ushort_t*)alloc((size_t)N * 128 * 2);
  ushort_t* hb = (ushort_t*)alloc((size_t)N * 128 * 2);
  ushort_t* hb2 = (ushort_t*)alloc((size_t)N * 128 * 2);
  ushort_t* p1 = (ushort_t*)alloc((size_t)N * 128 * 2);
  ushort_t* p2 = (ushort_t*)alloc((size_t)N * 128 * 2);
  ushort_t* xb = (ushort_t*)alloc((size_t)N * 64 * 2);
  ushort_t* wpk[3];
  for (int l = 0; l < 3; ++l) wpk[l] = (ushort_t*)alloc(2048 * 8 * 2);
  ushort_t* wpe = (ushort_t*)alloc(1024 * 8 * 2);

  struct G {
    float* dis; int* absRp; int* gmatC; int* gmatS; int* bsum;
    uint_t* parts; int* csrc; const int* src; const int* dst;
  } g[2];
  for (int i = 0; i < 2; ++i) {
    g[i].dis = (float*)alloc((size_t)N * 4);
    g[i].absRp = (int*)alloc((size_t)NBK * 65 * 4);
    g[i].gmatC = (int*)alloc((size_t)M * 4);
    g[i].gmatS = (int*)alloc((size_t)(M + 1) * 4);
    g[i].bsum = (int*)alloc(64 * 4);
    g[i].parts = (uint_t*)alloc((size_t)E * 4);
    g[i].csrc = (int*)alloc((size_t)(E + 64) * 4);   // +64 pad: 64-wide staging loads
  }
  g[0].src = ei1; g[0].dst = ei1 + E;
  g[1].src = ei2; g[1].dst = ei2 + E;

  int nScanM = (M + 8191) / 8192;

  // CSR build — both graphs per dispatch (gridDim.y = 2)
  k_phist<<<dim3(B, 2), 256, 0, stream>>>(g[0].dst, g[1].dst, g[0].gmatC, g[1].gmatC, E, B);
  k_scanA32<<<dim3(nScanM, 2), 256, 0, stream>>>(g[0].gmatC, g[1].gmatC,
                                                 g[0].gmatS, g[1].gmatS,
                                                 g[0].bsum, g[1].bsum, M);
  k_scanB<<<dim3(1, 2), 64, 0, stream>>>(g[0].bsum, g[1].bsum, nScanM);
  k_scanC32<<<dim3((M + 1 + 255) / 256, 2), 256, 0, stream>>>(g[0].gmatS, g[1].gmatS,
                                                              g[0].bsum, g[1].bsum, M, E);
  k_pscatter<<<dim3(B, 2), 256, 0, stream>>>(g[0].src, g[1].src, g[0].dst, g[1].dst,
                                             g[0].gmatS, g[1].gmatS,
                                             g[0].parts, g[1].parts, E, B);
  k_degb2<<<dim3(NBK, 2), 256, 0, stream>>>(g[0].parts, g[1].parts,
                                            g[0].gmatS, g[1].gmatS,
                                            g[0].absRp, g[1].absRp,
                                            g[0].csrc, g[1].csrc,
                                            g[0].dis, g[1].dis, B, N);

  // weights + input conversion (one fused dispatch)
  int total4 = N * 64 / 4;
  k_prep<<<dim3((total4 + 255) / 256, 5), 256, 0, stream>>>(
      conv_w[0], conv_w[1], conv_w[2], enc_w, wpk[0], wpk[1], wpk[2], wpe,
      x, xb, total4);

  int gb = (N + 63) / 64;
  int ga = (N + 3) / 4;
  // shared encoder -> h0
  k_gemm_enc<2><<<gb, 256, 0, stream>>>(xb, wpe, enc_b, h0, N);

  // layer 0: shared GEMM (dual output), dual-branch agg
  k_gemm_mfma2<<<gb, 256, 0, stream>>>(h0, wpk[0], g[0].dis, g[1].dis, hb, hb2, N);
  k_agg_dual<<<dim3(ga, 2), 256, 0, stream>>>((const char*)hb, (const char*)hb2,
                                              g[0].absRp, g[1].absRp,
                                              g[0].csrc, g[1].csrc,
                                              g[0].dis, g[1].dis,
                                              conv_b[0], ln_g[0], ln_b[0],
                                              (uint4*)p1, (uint4*)p2, N);
  // layers 1,2: dual-branch GEMM + dual-branch agg
  for (int l = 1; l < 3; ++l) {
    k_gemm_dual<<<dim3(gb, 2), 256, 0, stream>>>(p1, p2, wpk[l], g[0].dis, g[1].dis,
                                                 hb, hb2, N);
    k_agg_dual<<<dim3(ga, 2), 256, 0, stream>>>((const char*)hb, (const char*)hb2,
                                                g[0].absRp, g[1].absRp,
                                                g[0].csrc, g[1].csrc,
                                                g[0].dis, g[1].dis,
                                                conv_b[l], ln_g[l], ln_b[l],
                                                (uint4*)p1, (uint4*)p2, N);
  }

  k_out<<<(N + 255) / 256, 256, 0, stream>>>(p1, p2, out_w, out_b, out, N);
}